// Round 5
// baseline (1619.096 us; speedup 1.0000x reference)
//
#include <hip/hip_runtime.h>
#include <math.h>

// Problem constants (PCUTransformer)
#define B_    8
#define L_    1000
#define F_    7
#define DM_   512
#define H_    8
#define DFF_  2048
#define NL_   4
#define PRED_ 50
#define DK_   64
#define P_    16
#define EPS_  1e-5f
#define QKVS  1536      // fused qkv row stride

#define L2E_   1.4426950408889634f
#define C_QS   0.18033688011112042f   // 0.125 * log2(e) folded into q
#define WS_QP  16.0f                  // lmproj-q weight compensation: 16*C_QS = 2*log2e
#define BS_QP  2.8853900817779268f    // 2*log2(e) bias scale

typedef unsigned short u16;
typedef __bf16 bf16x8 __attribute__((ext_vector_type(8)));
typedef float  f32x4  __attribute__((ext_vector_type(4)));

// ---------------- helpers ----------------
__device__ inline float wave_reduce_sum(float x) {
#pragma unroll
  for (int off = 32; off >= 1; off >>= 1) x += __shfl_xor(x, off, 64);
  return x;
}
__device__ inline u16 f2bf(float f) {   // RNE float->bf16 bits
  unsigned int u = __float_as_uint(f);
  unsigned int r = u + 0x7FFFu + ((u >> 16) & 1u);
  return (u16)(r >> 16);
}
__device__ inline float bf2f(u16 u) { return __uint_as_float(((unsigned int)u) << 16); }
__device__ inline float fexp2(float x) { return __builtin_amdgcn_exp2f(x); }
__device__ inline float frcp(float x) { return __builtin_amdgcn_rcpf(x); }

union bfrag { bf16x8 b; uint4 q; u16 u[8]; };

// async global->LDS, 16B per lane; lds base wave-uniform, HW scatters lane*16
__device__ inline void gload16(const u16* g, u16* l) {
  __builtin_amdgcn_global_load_lds(
      (const __attribute__((address_space(1))) void*)g,
      (__attribute__((address_space(3))) void*)l, 16, 0, 0);
}

// ---------------- weight transpose-convert: out[n][k] = bf16(in[k][n]) ------
__global__ __launch_bounds__(256)
void transpose_w(const float* __restrict__ in, u16* __restrict__ out,
                 int K, int N, size_t in_lstride, size_t out_lstride,
                 int row_off, int out_ld) {
  __shared__ float tile[32][33];
  int z = blockIdx.z;
  int kk0 = blockIdx.y * 32, nn0 = blockIdx.x * 32;
  int tx = threadIdx.x & 31, ty = threadIdx.x >> 5;
  const float* ip = in + z * in_lstride;
  u16* op = out + z * out_lstride;
#pragma unroll
  for (int i = 0; i < 4; i++)
    tile[ty + i * 8][tx] = ip[(size_t)(kk0 + ty + i * 8) * N + nn0 + tx];
  __syncthreads();
#pragma unroll
  for (int i = 0; i < 4; i++)
    op[(size_t)(row_off + nn0 + ty + i * 8) * out_ld + kk0 + tx] = f2bf(tile[tx][ty + i * 8]);
}

// ---------------- V transpose: vt[b*8+h][dk][key(1024 pad)] = v -------------
__global__ __launch_bounds__(256)
void vtrans_kernel(const u16* __restrict__ qkv, u16* __restrict__ vtg) {
  __shared__ u16 tile[32][33];
  int bh = blockIdx.z;
  int b = bh >> 3, hh = bh & 7;
  int k0 = blockIdx.x * 32;   // key
  int d0 = blockIdx.y * 32;   // dk
  int tx = threadIdx.x & 31, ty = threadIdx.x >> 5;
#pragma unroll
  for (int i = 0; i < 4; i++) {
    int key = k0 + ty + i * 8;
    u16 v = 0;
    if (key < L_) v = qkv[(size_t)(b * L_ + key) * QKVS + 1024 + hh * DK_ + d0 + tx];
    tile[ty + i * 8][tx] = v;
  }
  __syncthreads();
#pragma unroll
  for (int i = 0; i < 4; i++)
    vtg[((size_t)bh * DK_ + d0 + ty + i * 8) * 1024 + k0 + tx] = tile[tx][ty + i * 8];
}

// ---------------- qkv bias concat -------------------------------------------
__global__ __launch_bounds__(256)
void concat_bias(const float* __restrict__ bq, const float* __restrict__ bk,
                 const float* __restrict__ bv, float* __restrict__ bqkv) {
  int i = blockIdx.x * 256 + threadIdx.x;
  int l = i / QKVS, j = i % QKVS;
  float v = (j < 512) ? bq[l * 512 + j] : (j < 1024) ? bk[l * 512 + j - 512]
                                                     : bv[l * 512 + j - 1024];
  bqkv[i] = v;
}

// ---------------- embedding -------------------------------------------------
__global__ __launch_bounds__(512)
void embed_kernel(const float* __restrict__ x, const float* __restrict__ emb_w,
                  const float* __restrict__ emb_b, const float* __restrict__ pe,
                  float* __restrict__ h, u16* __restrict__ h16) {
  int bl = blockIdx.x;
  int l = bl % L_;
  int d = threadIdx.x;
  const float* xr = x + (size_t)bl * F_;
  float acc = emb_b[d] + pe[(size_t)l * DM_ + d];
#pragma unroll
  for (int f = 0; f < F_; f++) acc = fmaf(xr[f], emb_w[f * DM_ + d], acc);
  h[(size_t)bl * DM_ + d] = acc;
  h16[(size_t)bl * DM_ + d] = f2bf(acc);
}

// ---------------- bf16 MFMA GEMM (m97 structure) ----------------------------
template<int BN>
__global__ __launch_bounds__(256)
void gemm16(const u16* __restrict__ A, const u16* __restrict__ Bt,
            const float* __restrict__ bias, const float* __restrict__ resid,
            float* __restrict__ C32, u16* __restrict__ C16,
            int M, int K, int N, int relu, int nscale, float sval) {
  constexpr int NTW = BN / 32;
  constexpr int BJ  = BN / 64;
  __shared__ u16 As[128 * 32];
  __shared__ u16 Bs[BN * 32];
  int t = threadIdx.x;
  int w = t >> 6, lane = t & 63;
  int wr = w >> 1, wc = w & 1;
  int mloc = lane & 15, quad = lane >> 4;
  int m0 = blockIdx.y * 128, n0 = blockIdx.x * BN;

  const u16* agp[2]; u16* alds[2];
#pragma unroll
  for (int j = 0; j < 2; j++) {
    int r = w * 32 + j * 16 + (lane >> 2);
    int gm = m0 + r; if (gm > M - 1) gm = M - 1;
    int ch = (lane & 3) ^ ((r >> 1) & 3);
    agp[j] = A + (size_t)gm * K + ch * 8;
    alds[j] = As + (w * 32 + j * 16) * 32;
  }
  const u16* bgp[BJ]; u16* blds[BJ];
#pragma unroll
  for (int j = 0; j < BJ; j++) {
    int r = w * (16 * BJ) + j * 16 + (lane >> 2);
    int ch = (lane & 3) ^ ((r >> 1) & 3);
    bgp[j] = Bt + (size_t)(n0 + r) * K + ch * 8;
    blds[j] = Bs + (w * (16 * BJ) + j * 16) * 32;
  }
  const u16* apt[4];
#pragma unroll
  for (int mi = 0; mi < 4; mi++) {
    int tr = wr * 64 + mi * 16 + mloc;
    apt[mi] = As + tr * 32 + (quad ^ ((tr >> 1) & 3)) * 8;
  }
  const u16* bpt[NTW];
#pragma unroll
  for (int nt = 0; nt < NTW; nt++) {
    int tr = wc * (BN / 2) + nt * 16 + mloc;
    bpt[nt] = Bs + tr * 32 + (quad ^ ((tr >> 1) & 3)) * 8;
  }

  f32x4 acc[4][NTW];
#pragma unroll
  for (int mi = 0; mi < 4; mi++)
#pragma unroll
    for (int nt = 0; nt < NTW; nt++) acc[mi][nt] = (f32x4){0.f, 0.f, 0.f, 0.f};

  for (int k0 = 0; k0 < K; k0 += 32) {
    __syncthreads();
    gload16(agp[0] + k0, alds[0]);
    gload16(agp[1] + k0, alds[1]);
#pragma unroll
    for (int j = 0; j < BJ; j++) gload16(bgp[j] + k0, blds[j]);
    __syncthreads();
    bf16x8 af[4], bv[NTW];
#pragma unroll
    for (int mi = 0; mi < 4; mi++) af[mi] = *(const bf16x8*)apt[mi];
#pragma unroll
    for (int nt = 0; nt < NTW; nt++) bv[nt] = *(const bf16x8*)bpt[nt];
#pragma unroll
    for (int mi = 0; mi < 4; mi++)
#pragma unroll
      for (int nt = 0; nt < NTW; nt++)
        acc[mi][nt] = __builtin_amdgcn_mfma_f32_16x16x32_bf16(af[mi], bv[nt], acc[mi][nt], 0, 0, 0);
  }

#pragma unroll
  for (int mi = 0; mi < 4; mi++) {
#pragma unroll
    for (int r = 0; r < 4; r++) {
      int m = m0 + wr * 64 + mi * 16 + quad * 4 + r;
      if (m >= M) continue;
      size_t crow = (size_t)m * N;
#pragma unroll
      for (int nt = 0; nt < NTW; nt++) {
        int n = n0 + wc * (BN / 2) + nt * 16 + mloc;
        float vsum = acc[mi][nt][r] + bias[n];
        if (resid) vsum += resid[crow + n];
        if (n < nscale) vsum *= sval;
        if (relu) vsum = fmaxf(vsum, 0.f);
        if (C32) C32[crow + n] = vsum;
        if (C16) C16[crow + n] = f2bf(vsum);
      }
    }
  }
}

// ---------------- fused learned-mask projection (q and k in one launch) -----
__global__ __launch_bounds__(128)
void lmproj_kernel(const u16* __restrict__ qkv,
                   const float* __restrict__ wq, const float* __restrict__ bq,
                   const float* __restrict__ wk, const float* __restrict__ bk,
                   u16* __restrict__ qp, u16* __restrict__ kp) {
  int bl = blockIdx.x;
  int which = blockIdx.y;            // 0 = q (scaled), 1 = k
  int t = threadIdx.x;
  int hh = t >> 4, p = t & 15;
  const float* w  = which ? wk : wq;
  const float* bb = which ? bk : bq;
  u16* dst        = which ? kp : qp;
  float wscale = which ? 1.0f : WS_QP;
  float bscale = which ? 1.0f : BS_QP;
  const u16* s = qkv + (size_t)bl * QKVS + (which ? 512 : 0) + hh * DK_;
  float acc = 0.f;
#pragma unroll
  for (int d = 0; d < DK_; d++) acc = fmaf(bf2f(s[d]), w[d * P_ + p], acc);
  dst[((size_t)bl * H_ + hh) * P_ + p] = f2bf(fmaf(acc, wscale, bb[p] * bscale));
}

// ---------------- MFMA flash attention, barrier-free, global B-frags --------
// All K/V/kp MFMA B-fragments load directly from global (L1/L2-resident);
// only the per-wave P C->A transform uses LDS. No __syncthreads in K-loop.
#define KT  128
#define LDP 136   // Ps row stride (272B = 17*16B, 16B-aligned)
__global__ __launch_bounds__(256, 4)
void attn_mfma_kernel(const u16* __restrict__ qkv, const u16* __restrict__ qpg,
                      const u16* __restrict__ kpg, const u16* __restrict__ vtg,
                      u16* __restrict__ ctx) {
  __shared__ u16 Ps[4 * 16 * LDP]; // per-wave P[16][128]

  int qt = blockIdx.x, bh = blockIdx.y;
  int b = bh >> 3, hh = bh & 7;
  int l0 = qt * 64;
  int t = threadIdx.x;
  int wv = t >> 6, lane = t & 63;
  int m = lane & 15, quad = lane >> 4;

  // Q (pre-scaled by 0.125*log2e in GEMM) + qp (pre-scaled by 2*log2e)
  int lq = l0 + wv * 16 + m; if (lq > L_ - 1) lq = L_ - 1;
  const u16* qrow = qkv + (size_t)(b * L_ + lq) * QKVS + hh * DK_;
  bf16x8 qa0 = *(const bf16x8*)(qrow + quad * 8);
  bf16x8 qa1 = *(const bf16x8*)(qrow + 32 + quad * 8);
  bfrag qpa;
  if (quad < 2) {
    qpa.q = *(const uint4*)(qpg + ((size_t)(b * L_ + lq) * H_ + hh) * P_ + quad * 8);
  } else {
    qpa.q = make_uint4(0u, 0u, 0u, 0u);
  }

  const u16* kbase  = qkv + (size_t)b * L_ * QKVS + 512 + hh * DK_;
  const u16* kpbase = kpg + ((size_t)b * L_ * H_ + hh) * P_;
  const u16* vbase  = vtg + (size_t)bh * DK_ * 1024 + (size_t)m * 1024 + quad * 8;

  f32x4 O[4];
#pragma unroll
  for (int nt = 0; nt < 4; nt++) O[nt] = (f32x4){0.f, 0.f, 0.f, 0.f};
  float mrun[4] = {-3e38f, -3e38f, -3e38f, -3e38f};
  float lrun[4] = {0.f, 0.f, 0.f, 0.f};

  u16* pw = Ps + wv * (16 * LDP);
  const u16* pr0 = pw + m * LDP + quad * 8;

  for (int s0 = 0; s0 < L_; s0 += KT) {
    // ---- scores: S = (log2e/8)qk + log2-domain tanh bias ----
    float scp[8][4];
    const f32x4 zz = (f32x4){0.f, 0.f, 0.f, 0.f};
#pragma unroll
    for (int nt = 0; nt < 8; nt++) {
      int srow = s0 + nt * 16 + m; if (srow > L_ - 1) srow = L_ - 1;
      const u16* kb = kbase + (size_t)srow * QKVS;
      f32x4 sacc = __builtin_amdgcn_mfma_f32_16x16x32_bf16(qa0, *(const bf16x8*)(kb + quad * 8), zz, 0, 0, 0);
      sacc = __builtin_amdgcn_mfma_f32_16x16x32_bf16(qa1, *(const bf16x8*)(kb + 32 + quad * 8), sacc, 0, 0, 0);
      bfrag kpf;
      if (quad < 2) kpf.q = *(const uint4*)(kpbase + (size_t)srow * (H_ * P_) + quad * 8);
      else          kpf.q = make_uint4(0u, 0u, 0u, 0u);
      f32x4 macc = __builtin_amdgcn_mfma_f32_16x16x32_bf16(qpa.b, kpf.b, zz, 0, 0, 0);
#pragma unroll
      for (int r = 0; r < 4; r++) {
        // macc = 2*log2e*x -> e=exp(2x); tanh_l2 = log2e - 2*log2e/(e+1)
        float e = fexp2(macc[r]);
        float d = frcp(e + 1.f);
        float th = fmaf(d, -2.f * L2E_, L2E_);
        scp[nt][r] = sacc[r] + th;
      }
    }
    if (s0 + KT > L_) {   // tail masking (last tile only)
#pragma unroll
      for (int nt = 0; nt < 8; nt++) {
        if (s0 + nt * 16 + m >= L_) {
#pragma unroll
          for (int r = 0; r < 4; r++) scp[nt][r] = -3e38f;
        }
      }
    }

    // ---- online softmax in exp2 domain ----
    float mnew[4], alpha[4];
#pragma unroll
    for (int r = 0; r < 4; r++) {
      float rm = scp[0][r];
#pragma unroll
      for (int nt = 1; nt < 8; nt++) rm = fmaxf(rm, scp[nt][r]);
#pragma unroll
      for (int msk = 1; msk < 16; msk <<= 1) rm = fmaxf(rm, __shfl_xor(rm, msk, 64));
      mnew[r] = fmaxf(mrun[r], rm);
      alpha[r] = fexp2(mrun[r] - mnew[r]);
      mrun[r] = mnew[r];
    }
    float rs[4] = {0.f, 0.f, 0.f, 0.f};
#pragma unroll
    for (int nt = 0; nt < 8; nt++)
#pragma unroll
      for (int r = 0; r < 4; r++) {
        float p = fexp2(scp[nt][r] - mnew[r]);
        scp[nt][r] = p;
        rs[r] += p;
      }
#pragma unroll
    for (int r = 0; r < 4; r++) {
#pragma unroll
      for (int msk = 1; msk < 16; msk <<= 1) rs[r] += __shfl_xor(rs[r], msk, 64);
      lrun[r] = lrun[r] * alpha[r] + rs[r];
    }
    f32x4 av = (f32x4){alpha[0], alpha[1], alpha[2], alpha[3]};
#pragma unroll
    for (int nt = 0; nt < 4; nt++) O[nt] *= av;

    // ---- P: C-layout -> per-wave LDS -> A-layout (same-wave, no barrier) ----
#pragma unroll
    for (int nt = 0; nt < 8; nt++)
#pragma unroll
      for (int r = 0; r < 4; r++)
        pw[(quad * 4 + r) * LDP + nt * 16 + m] = f2bf(scp[nt][r]);

#pragma unroll
    for (int kc = 0; kc < 4; kc++) {
      bf16x8 pa = *(const bf16x8*)(pr0 + kc * 32);
#pragma unroll
      for (int nt = 0; nt < 4; nt++) {
        const u16* vb = vbase + (size_t)nt * 16 * 1024 + s0 + kc * 32;
        O[nt] = __builtin_amdgcn_mfma_f32_16x16x32_bf16(pa, *(const bf16x8*)vb, O[nt], 0, 0, 0);
      }
    }
  }

  float inv[4];
#pragma unroll
  for (int r = 0; r < 4; r++) inv[r] = frcp(lrun[r]);
#pragma unroll
  for (int r = 0; r < 4; r++) {
    int l = l0 + wv * 16 + quad * 4 + r;
    if (l >= L_) continue;
    u16* crow = ctx + ((size_t)(b * L_ + l)) * DM_ + hh * DK_;
#pragma unroll
    for (int nt = 0; nt < 4; nt++) crow[nt * 16 + m] = f2bf(O[nt][r] * inv[r]);
  }
}

// ---------------- layernorm -------------------------------------------------
__global__ __launch_bounds__(256)
void ln_kernel(const float* __restrict__ a, const float* __restrict__ badd,
               const float* __restrict__ g, const float* __restrict__ be,
               float* __restrict__ o, u16* __restrict__ o16) {
  int row = blockIdx.x;
  int t = threadIdx.x;
  size_t base = (size_t)row * DM_;
  float x0 = a[base + t], x1 = a[base + t + 256];
  if (badd) { x0 += badd[base + t]; x1 += badd[base + t + 256]; }
  float s = wave_reduce_sum(x0 + x1);
  float ss = wave_reduce_sum(x0 * x0 + x1 * x1);
  __shared__ float sh_s[4], sh_ss[4];
  int wv = t >> 6, lane = t & 63;
  if (lane == 0) { sh_s[wv] = s; sh_ss[wv] = ss; }
  __syncthreads();
  float S = sh_s[0] + sh_s[1] + sh_s[2] + sh_s[3];
  float SS = sh_ss[0] + sh_ss[1] + sh_ss[2] + sh_ss[3];
  float mean = S * (1.0f / DM_);
  float var = SS * (1.0f / DM_) - mean * mean;
  float rstd = rsqrtf(var + EPS_);
  float r0 = (x0 - mean) * rstd * g[t] + be[t];
  float r1 = (x1 - mean) * rstd * g[t + 256] + be[t + 256];
  o[base + t] = r0; o[base + t + 256] = r1;
  if (o16) { o16[base + t] = f2bf(r0); o16[base + t + 256] = f2bf(r1); }
}

// ---------------- fused double layernorm ------------------------------------
__global__ __launch_bounds__(256)
void ln2x_kernel(const float* __restrict__ hin, const float* __restrict__ y,
                 const float* __restrict__ g, const float* __restrict__ be,
                 float* __restrict__ o32, u16* __restrict__ o16) {
  int row = blockIdx.x;
  int t = threadIdx.x;
  size_t base = (size_t)row * DM_;
  float y0 = y[base + t], y1 = y[base + t + 256];
  float x0 = hin[base + t] + y0, x1 = hin[base + t + 256] + y1;
  __shared__ float sh_s[4], sh_ss[4];
  int wv = t >> 6, lane = t & 63;
  float g0 = g[t], g1v = g[t + 256], b0 = be[t], b1v = be[t + 256];

  float s = wave_reduce_sum(x0 + x1);
  float ss = wave_reduce_sum(x0 * x0 + x1 * x1);
  if (lane == 0) { sh_s[wv] = s; sh_ss[wv] = ss; }
  __syncthreads();
  float S = sh_s[0] + sh_s[1] + sh_s[2] + sh_s[3];
  float SS = sh_ss[0] + sh_ss[1] + sh_ss[2] + sh_ss[3];
  float mean = S * (1.0f / DM_);
  float var = SS * (1.0f / DM_) - mean * mean;
  float rstd = rsqrtf(var + EPS_);
  float h20 = (x0 - mean) * rstd * g0 + b0 + y0;
  float h21 = (x1 - mean) * rstd * g1v + b1v + y1;
  __syncthreads();

  s = wave_reduce_sum(h20 + h21);
  ss = wave_reduce_sum(h20 * h20 + h21 * h21);
  if (lane == 0) { sh_s[wv] = s; sh_ss[wv] = ss; }
  __syncthreads();
  S = sh_s[0] + sh_s[1] + sh_s[2] + sh_s[3];
  SS = sh_ss[0] + sh_ss[1] + sh_ss[2] + sh_ss[3];
  mean = S * (1.0f / DM_);
  var = SS * (1.0f / DM_) - mean * mean;
  rstd = rsqrtf(var + EPS_);
  float r0 = (h20 - mean) * rstd * g0 + b0;
  float r1 = (h21 - mean) * rstd * g1v + b1v;
  o32[base + t] = r0; o32[base + t + 256] = r1;
  if (o16) { o16[base + t] = f2bf(r0); o16[base + t + 256] = f2bf(r1); }
}

// ---------------- final head ------------------------------------------------
__global__ __launch_bounds__(512)
void final_kernel(const float* __restrict__ h, const float* __restrict__ gn,
                  const float* __restrict__ bn, const float* __restrict__ fcw,
                  const float* __restrict__ fcb, float* __restrict__ out) {
  int b = blockIdx.x;
  int t = threadIdx.x;
  size_t base = ((size_t)b * L_ + (L_ - 1)) * DM_;
  float x = h[base + t];
  float s = wave_reduce_sum(x);
  float ss = wave_reduce_sum(x * x);
  __shared__ float sh_s[8], sh_ss[8];
  int wv = t >> 6, lane = t & 63;
  if (lane == 0) { sh_s[wv] = s; sh_ss[wv] = ss; }
  __syncthreads();
  float S = 0.f, SS = 0.f;
#pragma unroll
  for (int i = 0; i < 8; i++) { S += sh_s[i]; SS += sh_ss[i]; }
  float mean = S * (1.0f / DM_);
  float var = SS * (1.0f / DM_) - mean * mean;
  float rstd = rsqrtf(var + EPS_);
  __shared__ float hn[DM_];
  hn[t] = (x - mean) * rstd * gn[t] + bn[t];
  __syncthreads();
  if (t < PRED_) {
    float acc = fcb[t];
#pragma unroll 8
    for (int d = 0; d < DM_; d++) acc = fmaf(hn[d], fcw[d * PRED_ + t], acc);
    out[b * PRED_ + t] = acc;
  }
}

// ---------------- driver ----------------
extern "C" void kernel_launch(void* const* d_in, const int* in_sizes, int n_in,
                              void* d_out, int out_size, void* d_ws, size_t ws_size,
                              hipStream_t stream) {
  const float* x     = (const float*)d_in[0];
  const float* emb_w = (const float*)d_in[1];
  const float* emb_b = (const float*)d_in[2];
  const float* pe    = (const float*)d_in[3];
  const float* Wq = (const float*)d_in[4];  const float* bq = (const float*)d_in[5];
  const float* Wk = (const float*)d_in[6];  const float* bk = (const float*)d_in[7];
  const float* Wv = (const float*)d_in[8];  const float* bv = (const float*)d_in[9];
  const float* Wo = (const float*)d_in[10]; const float* bo = (const float*)d_in[11];
  const float* W1 = (const float*)d_in[12]; const float* b1 = (const float*)d_in[13];
  const float* W2 = (const float*)d_in[14]; const float* b2 = (const float*)d_in[15];
  const float* g1 = (const float*)d_in[16]; const float* be1 = (const float*)d_in[17];
  const float* g2 = (const float*)d_in[18]; const float* be2 = (const float*)d_in[19];
  const float* lm_qw = (const float*)d_in[20]; const float* lm_qb = (const float*)d_in[21];
  const float* lm_kw = (const float*)d_in[22]; const float* lm_kb = (const float*)d_in[23];
  const float* gn = (const float*)d_in[24]; const float* bn = (const float*)d_in[25];
  const float* fc_w = (const float*)d_in[26]; const float* fc_b = (const float*)d_in[27];
  float* out = (float*)d_out;

  const size_t ROWS = (size_t)B_ * L_;     // 8000
  u16* qkv16 = (u16*)d_ws;                               // [8000][1536]
  u16* ctx16 = qkv16 + ROWS * QKVS;                      // [8000][512]
  u16* ffn1  = qkv16;                                    // [8000][2048] alias
  u16* h16   = ctx16 + ROWS * DM_;                       // [8000][512]
  u16* qp16  = h16 + ROWS * DM_;                         // [8000][128]
  u16* kp16  = qp16 + ROWS * H_ * P_;
  u16* Wqkv_t = kp16 + ROWS * H_ * P_;                   // [NL][1536][512]
  u16* Wo_t   = Wqkv_t + (size_t)NL_ * QKVS * DM_;       // [NL][512][512]
  u16* W1_t   = Wo_t + (size_t)NL_ * DM_ * DM_;          // [NL][2048][512]
  u16* W2_t   = W1_t + (size_t)NL_ * DFF_ * DM_;         // [NL][512][2048]
  float* h32  = (float*)(W2_t + (size_t)NL_ * DM_ * DFF_);
  float* t0   = h32 + ROWS * DM_;
  float* bqkv = t0 + ROWS * DM_;                         // [NL][1536]
  u16* vtg    = (u16*)t0;   // [64][64][1024] = 8.4 MB, aliases t0 (dead during attn)

  transpose_w<<<dim3(16, 16, NL_), 256, 0, stream>>>(Wq, Wqkv_t, DM_, DM_, (size_t)DM_ * DM_, (size_t)QKVS * DM_, 0, DM_);
  transpose_w<<<dim3(16, 16, NL_), 256, 0, stream>>>(Wk, Wqkv_t, DM_, DM_, (size_t)DM_ * DM_, (size_t)QKVS * DM_, 512, DM_);
  transpose_w<<<dim3(16, 16, NL_), 256, 0, stream>>>(Wv, Wqkv_t, DM_, DM_, (size_t)DM_ * DM_, (size_t)QKVS * DM_, 1024, DM_);
  transpose_w<<<dim3(16, 16, NL_), 256, 0, stream>>>(Wo, Wo_t, DM_, DM_, (size_t)DM_ * DM_, (size_t)DM_ * DM_, 0, DM_);
  transpose_w<<<dim3(64, 16, NL_), 256, 0, stream>>>(W1, W1_t, DM_, DFF_, (size_t)DM_ * DFF_, (size_t)DFF_ * DM_, 0, DM_);
  transpose_w<<<dim3(16, 64, NL_), 256, 0, stream>>>(W2, W2_t, DFF_, DM_, (size_t)DFF_ * DM_, (size_t)DM_ * DFF_, 0, DFF_);
  concat_bias<<<NL_ * QKVS / 256, 256, 0, stream>>>(bq, bk, bv, bqkv);

  embed_kernel<<<dim3((unsigned)ROWS), 512, 0, stream>>>(x, emb_w, emb_b, pe, h32, h16);

  dim3 g_qkv(QKVS / 128, 63);
  dim3 g_ffn1(DFF_ / 128, 63);
  dim3 g_n512(DM_ / 64, 63);
  dim3 g_attn(16, B_ * H_);
  dim3 g_lm((unsigned)ROWS, 2);

  for (int i = 0; i < NL_; i++) {
    gemm16<128><<<g_qkv, 256, 0, stream>>>(h16, Wqkv_t + (size_t)i * QKVS * DM_,
        bqkv + i * QKVS, nullptr, nullptr, qkv16, 8000, DM_, QKVS, 0, 512, C_QS);

    lmproj_kernel<<<g_lm, 128, 0, stream>>>(qkv16, lm_qw, lm_qb, lm_kw, lm_kb, qp16, kp16);
    vtrans_kernel<<<dim3(32, 2, B_ * H_), 256, 0, stream>>>(qkv16, vtg);

    attn_mfma_kernel<<<g_attn, 256, 0, stream>>>(qkv16, qp16, kp16, vtg, ctx16);

    gemm16<64><<<g_n512, 256, 0, stream>>>(ctx16, Wo_t + (size_t)i * DM_ * DM_,
        bo + i * DM_, h32, t0, nullptr, 8000, DM_, DM_, 0, 0, 1.0f);
    ln_kernel<<<dim3((unsigned)ROWS), 256, 0, stream>>>(t0, nullptr, g1 + i * DM_, be1 + i * DM_, h32, h16);

    gemm16<128><<<g_ffn1, 256, 0, stream>>>(h16, W1_t + (size_t)i * DFF_ * DM_,
        b1 + i * DFF_, nullptr, nullptr, ffn1, 8000, DM_, DFF_, 1, 0, 1.0f);
    gemm16<64><<<g_n512, 256, 0, stream>>>(ffn1, W2_t + (size_t)i * DM_ * DFF_,
        b2 + i * DM_, nullptr, t0, nullptr, 8000, DFF_, DM_, 0, 0, 1.0f);

    ln2x_kernel<<<dim3((unsigned)ROWS), 256, 0, stream>>>(h32, t0, g2 + i * DM_, be2 + i * DM_, h32, h16);
  }

  final_kernel<<<B_, 512, 0, stream>>>(h32, gn, bn, fc_w, fc_b, out);
}

// Round 6
// 1330.220 us; speedup vs baseline: 1.2172x; 1.2172x over previous
//
#include <hip/hip_runtime.h>
#include <math.h>

// Problem constants (PCUTransformer)
#define B_    8
#define L_    1000
#define F_    7
#define DM_   512
#define H_    8
#define DFF_  2048
#define NL_   4
#define PRED_ 50
#define DK_   64
#define P_    16
#define EPS_  1e-5f
#define QKVS  1536      // fused qkv row stride

#define L2E_   1.4426950408889634f
#define C_QS   0.18033688011112042f   // 0.125 * log2(e) folded into q
#define WS_QP  16.0f                  // lmproj-q weight compensation: 16*C_QS = 2*log2e
#define BS_QP  2.8853900817779268f    // 2*log2(e) bias scale

typedef unsigned short u16;
typedef __bf16 bf16x8 __attribute__((ext_vector_type(8)));
typedef float  f32x4  __attribute__((ext_vector_type(4)));

// ---------------- helpers ----------------
__device__ inline float wave_reduce_sum(float x) {
#pragma unroll
  for (int off = 32; off >= 1; off >>= 1) x += __shfl_xor(x, off, 64);
  return x;
}
__device__ inline u16 f2bf(float f) {   // RNE float->bf16 bits
  unsigned int u = __float_as_uint(f);
  unsigned int r = u + 0x7FFFu + ((u >> 16) & 1u);
  return (u16)(r >> 16);
}
__device__ inline float bf2f(u16 u) { return __uint_as_float(((unsigned int)u) << 16); }
__device__ inline float fexp2(float x) { return __builtin_amdgcn_exp2f(x); }
__device__ inline float frcp(float x) { return __builtin_amdgcn_rcpf(x); }

union bfrag { bf16x8 b; uint4 q; u16 u[8]; };

// async global->LDS, 16B per lane; lds base wave-uniform, HW scatters lane*16
__device__ inline void gload16(const u16* g, u16* l) {
  __builtin_amdgcn_global_load_lds(
      (const __attribute__((address_space(1))) void*)g,
      (__attribute__((address_space(3))) void*)l, 16, 0, 0);
}

// ---------------- weight transpose-convert: out[n][k] = bf16(in[k][n]) ------
__global__ __launch_bounds__(256)
void transpose_w(const float* __restrict__ in, u16* __restrict__ out,
                 int K, int N, size_t in_lstride, size_t out_lstride,
                 int row_off, int out_ld) {
  __shared__ float tile[32][33];
  int z = blockIdx.z;
  int kk0 = blockIdx.y * 32, nn0 = blockIdx.x * 32;
  int tx = threadIdx.x & 31, ty = threadIdx.x >> 5;
  const float* ip = in + z * in_lstride;
  u16* op = out + z * out_lstride;
#pragma unroll
  for (int i = 0; i < 4; i++)
    tile[ty + i * 8][tx] = ip[(size_t)(kk0 + ty + i * 8) * N + nn0 + tx];
  __syncthreads();
#pragma unroll
  for (int i = 0; i < 4; i++)
    op[(size_t)(row_off + nn0 + ty + i * 8) * out_ld + kk0 + tx] = f2bf(tile[tx][ty + i * 8]);
}

// ---------------- V transpose: vt[b*8+h][dk][key(1024 pad)] = v -------------
__global__ __launch_bounds__(256)
void vtrans_kernel(const u16* __restrict__ qkv, u16* __restrict__ vtg) {
  __shared__ u16 tile[32][33];
  int bh = blockIdx.z;
  int b = bh >> 3, hh = bh & 7;
  int k0 = blockIdx.x * 32;   // key
  int d0 = blockIdx.y * 32;   // dk
  int tx = threadIdx.x & 31, ty = threadIdx.x >> 5;
#pragma unroll
  for (int i = 0; i < 4; i++) {
    int key = k0 + ty + i * 8;
    u16 v = 0;
    if (key < L_) v = qkv[(size_t)(b * L_ + key) * QKVS + 1024 + hh * DK_ + d0 + tx];
    tile[ty + i * 8][tx] = v;
  }
  __syncthreads();
#pragma unroll
  for (int i = 0; i < 4; i++)
    vtg[((size_t)bh * DK_ + d0 + ty + i * 8) * 1024 + k0 + tx] = tile[tx][ty + i * 8];
}

// ---------------- qkv bias concat -------------------------------------------
__global__ __launch_bounds__(256)
void concat_bias(const float* __restrict__ bq, const float* __restrict__ bk,
                 const float* __restrict__ bv, float* __restrict__ bqkv) {
  int i = blockIdx.x * 256 + threadIdx.x;
  int l = i / QKVS, j = i % QKVS;
  float v = (j < 512) ? bq[l * 512 + j] : (j < 1024) ? bk[l * 512 + j - 512]
                                                     : bv[l * 512 + j - 1024];
  bqkv[i] = v;
}

// ---------------- embedding -------------------------------------------------
__global__ __launch_bounds__(512)
void embed_kernel(const float* __restrict__ x, const float* __restrict__ emb_w,
                  const float* __restrict__ emb_b, const float* __restrict__ pe,
                  float* __restrict__ h, u16* __restrict__ h16) {
  int bl = blockIdx.x;
  int l = bl % L_;
  int d = threadIdx.x;
  const float* xr = x + (size_t)bl * F_;
  float acc = emb_b[d] + pe[(size_t)l * DM_ + d];
#pragma unroll
  for (int f = 0; f < F_; f++) acc = fmaf(xr[f], emb_w[f * DM_ + d], acc);
  h[(size_t)bl * DM_ + d] = acc;
  h16[(size_t)bl * DM_ + d] = f2bf(acc);
}

// ---------------- bf16 MFMA GEMM (m97 structure) ----------------------------
template<int BN>
__global__ __launch_bounds__(256)
void gemm16(const u16* __restrict__ A, const u16* __restrict__ Bt,
            const float* __restrict__ bias, const float* __restrict__ resid,
            float* __restrict__ C32, u16* __restrict__ C16,
            int M, int K, int N, int relu, int nscale, float sval) {
  constexpr int NTW = BN / 32;
  constexpr int BJ  = BN / 64;
  __shared__ u16 As[128 * 32];
  __shared__ u16 Bs[BN * 32];
  int t = threadIdx.x;
  int w = t >> 6, lane = t & 63;
  int wr = w >> 1, wc = w & 1;
  int mloc = lane & 15, quad = lane >> 4;
  int m0 = blockIdx.y * 128, n0 = blockIdx.x * BN;

  const u16* agp[2]; u16* alds[2];
#pragma unroll
  for (int j = 0; j < 2; j++) {
    int r = w * 32 + j * 16 + (lane >> 2);
    int gm = m0 + r; if (gm > M - 1) gm = M - 1;
    int ch = (lane & 3) ^ ((r >> 1) & 3);
    agp[j] = A + (size_t)gm * K + ch * 8;
    alds[j] = As + (w * 32 + j * 16) * 32;
  }
  const u16* bgp[BJ]; u16* blds[BJ];
#pragma unroll
  for (int j = 0; j < BJ; j++) {
    int r = w * (16 * BJ) + j * 16 + (lane >> 2);
    int ch = (lane & 3) ^ ((r >> 1) & 3);
    bgp[j] = Bt + (size_t)(n0 + r) * K + ch * 8;
    blds[j] = Bs + (w * (16 * BJ) + j * 16) * 32;
  }
  const u16* apt[4];
#pragma unroll
  for (int mi = 0; mi < 4; mi++) {
    int tr = wr * 64 + mi * 16 + mloc;
    apt[mi] = As + tr * 32 + (quad ^ ((tr >> 1) & 3)) * 8;
  }
  const u16* bpt[NTW];
#pragma unroll
  for (int nt = 0; nt < NTW; nt++) {
    int tr = wc * (BN / 2) + nt * 16 + mloc;
    bpt[nt] = Bs + tr * 32 + (quad ^ ((tr >> 1) & 3)) * 8;
  }

  f32x4 acc[4][NTW];
#pragma unroll
  for (int mi = 0; mi < 4; mi++)
#pragma unroll
    for (int nt = 0; nt < NTW; nt++) acc[mi][nt] = (f32x4){0.f, 0.f, 0.f, 0.f};

  for (int k0 = 0; k0 < K; k0 += 32) {
    __syncthreads();
    gload16(agp[0] + k0, alds[0]);
    gload16(agp[1] + k0, alds[1]);
#pragma unroll
    for (int j = 0; j < BJ; j++) gload16(bgp[j] + k0, blds[j]);
    __syncthreads();
    bf16x8 af[4], bv[NTW];
#pragma unroll
    for (int mi = 0; mi < 4; mi++) af[mi] = *(const bf16x8*)apt[mi];
#pragma unroll
    for (int nt = 0; nt < NTW; nt++) bv[nt] = *(const bf16x8*)bpt[nt];
#pragma unroll
    for (int mi = 0; mi < 4; mi++)
#pragma unroll
      for (int nt = 0; nt < NTW; nt++)
        acc[mi][nt] = __builtin_amdgcn_mfma_f32_16x16x32_bf16(af[mi], bv[nt], acc[mi][nt], 0, 0, 0);
  }

#pragma unroll
  for (int mi = 0; mi < 4; mi++) {
#pragma unroll
    for (int r = 0; r < 4; r++) {
      int m = m0 + wr * 64 + mi * 16 + quad * 4 + r;
      if (m >= M) continue;
      size_t crow = (size_t)m * N;
#pragma unroll
      for (int nt = 0; nt < NTW; nt++) {
        int n = n0 + wc * (BN / 2) + nt * 16 + mloc;
        float vsum = acc[mi][nt][r] + bias[n];
        if (resid) vsum += resid[crow + n];
        if (n < nscale) vsum *= sval;
        if (relu) vsum = fmaxf(vsum, 0.f);
        if (C32) C32[crow + n] = vsum;
        if (C16) C16[crow + n] = f2bf(vsum);
      }
    }
  }
}

// ---------------- fused learned-mask projection (q and k in one launch) -----
__global__ __launch_bounds__(128)
void lmproj_kernel(const u16* __restrict__ qkv,
                   const float* __restrict__ wq, const float* __restrict__ bq,
                   const float* __restrict__ wk, const float* __restrict__ bk,
                   u16* __restrict__ qp, u16* __restrict__ kp) {
  int bl = blockIdx.x;
  int which = blockIdx.y;            // 0 = q (scaled), 1 = k
  int t = threadIdx.x;
  int hh = t >> 4, p = t & 15;
  const float* w  = which ? wk : wq;
  const float* bb = which ? bk : bq;
  u16* dst        = which ? kp : qp;
  float wscale = which ? 1.0f : WS_QP;
  float bscale = which ? 1.0f : BS_QP;
  const u16* s = qkv + (size_t)bl * QKVS + (which ? 512 : 0) + hh * DK_;
  float acc = 0.f;
#pragma unroll
  for (int d = 0; d < DK_; d++) acc = fmaf(bf2f(s[d]), w[d * P_ + p], acc);
  dst[((size_t)bl * H_ + hh) * P_ + p] = f2bf(fmaf(acc, wscale, bb[p] * bscale));
}

// ---------------- MFMA flash attention, LDS-staged, Ps aliases Ks -----------
// 128-key tiles; Ks (score phase) and Ps (PV phase) share one LDS region,
// separated by a barrier. Kp stores only the 16 real p-dims (qp A-frag is
// zero in quads 2-3, so the k=16..31 half contributes 0 regardless of B).
#define KT   128
#define LDP  136   // Ps row stride (272B = 17*16B)
#define KPLD 24    // Kp row stride (48B = 3*16B)
__global__ __launch_bounds__(256, 4)
void attn_mfma_kernel(const u16* __restrict__ qkv, const u16* __restrict__ qpg,
                      const u16* __restrict__ kpg, const u16* __restrict__ vtg,
                      u16* __restrict__ ctx) {
  __shared__ u16 KsPs[4 * 16 * LDP];   // 17408B; Ks view = first 128*64 elems
  __shared__ u16 Vt[64 * KT];          // 16384B  [dk][key], XOR-swizzled
  __shared__ u16 Kp[KT * KPLD];        // 6144B   [key][p 0..15 (+pad)]

  int qt = blockIdx.x, bh = blockIdx.y;
  int b = bh >> 3, hh = bh & 7;
  int l0 = qt * 64;
  int t = threadIdx.x;
  int wv = t >> 6, lane = t & 63;
  int m = lane & 15, quad = lane >> 4;

  // Q (pre-scaled by 0.125*log2e in GEMM) + qp (pre-scaled by 2*log2e)
  int lq = l0 + wv * 16 + m; if (lq > L_ - 1) lq = L_ - 1;
  const u16* qrow = qkv + (size_t)(b * L_ + lq) * QKVS + hh * DK_;
  bf16x8 qa0 = *(const bf16x8*)(qrow + quad * 8);
  bf16x8 qa1 = *(const bf16x8*)(qrow + 32 + quad * 8);
  bfrag qpa;
  if (quad < 2) {
    qpa.q = *(const uint4*)(qpg + ((size_t)(b * L_ + lq) * H_ + hh) * P_ + quad * 8);
  } else {
    qpa.q = make_uint4(0u, 0u, 0u, 0u);
  }

  // staging addresses (verified in R4):
  // Ks: row (t>>3), slot (t&7) holds global chunk slot^(row&7) -> read un-XORs
  const u16* ks_g = qkv + ((size_t)b * L_ + (t >> 3)) * QKVS + 512 + hh * DK_
                    + ((t & 7) ^ ((t >> 3) & 7)) * 8;
  u16* ks_l = KsPs + (t >> 6) * 512;
  // Vt: row (t>>4) of dk, slot (t&15) holds chunk slot^(row&15)
  const u16* vt_g = vtg + ((size_t)bh * DK_ + (t >> 4)) * 1024
                    + (((t & 15) ^ (t >> 4)) * 8);
  u16* vt_l = Vt + (t >> 6) * 512;

  f32x4 O[4];
#pragma unroll
  for (int nt = 0; nt < 4; nt++) O[nt] = (f32x4){0.f, 0.f, 0.f, 0.f};
  float mrun[4] = {-3e38f, -3e38f, -3e38f, -3e38f};
  float lrun[4] = {0.f, 0.f, 0.f, 0.f};

  u16* pw = KsPs + wv * (16 * LDP);
  const u16* pr0 = pw + m * LDP + quad * 8;

  for (int s0 = 0; s0 < L_; s0 += KT) {
    // kp tile -> VGPR (global reads, no LDS hazard yet)
    uint4 p0, p1;
    if (t < KT) {
      int sg2 = s0 + t; if (sg2 > L_ - 1) sg2 = L_ - 1;
      const u16* pr = kpg + ((size_t)(b * L_ + sg2) * H_ + hh) * P_;
      p0 = *(const uint4*)(pr);
      p1 = *(const uint4*)(pr + 8);
    }
    __syncthreads();   // B1: all waves done with prev Ps/Vt/Kp reads
#pragma unroll
    for (int j = 0; j < 4; j++) {
      gload16(ks_g + ((size_t)s0 + j * 32) * QKVS, ks_l + j * 2048);
      gload16(vt_g + s0 + (size_t)j * 16 * 1024, vt_l + j * 2048);
    }
    if (t < KT) {
      *(uint4*)&Kp[t * KPLD]     = p0;
      *(uint4*)&Kp[t * KPLD + 8] = p1;
    }
    __syncthreads();   // B2: tile staged (vmcnt+lgkm drain)

    // ---- scores: S = (log2e/8)qk + log2-domain tanh bias ----
    float scp[8][4];
    const f32x4 zz = (f32x4){0.f, 0.f, 0.f, 0.f};
#pragma unroll
    for (int nt = 0; nt < 8; nt++) {
      const u16* kb = KsPs + (nt * 16 + m) * 64;
      int x0 = ((quad) ^ (m & 7)) * 8;
      int x1 = ((4 + quad) ^ (m & 7)) * 8;
      f32x4 sacc = __builtin_amdgcn_mfma_f32_16x16x32_bf16(qa0, *(const bf16x8*)(kb + x0), zz, 0, 0, 0);
      sacc = __builtin_amdgcn_mfma_f32_16x16x32_bf16(qa1, *(const bf16x8*)(kb + x1), sacc, 0, 0, 0);
      // Kp read: quads 2-3 reuse quads 0-1 data (finite); qpa zeros kill k>=16
      bf16x8 kpf = *(const bf16x8*)(Kp + (nt * 16 + m) * KPLD + (quad & 1) * 8);
      f32x4 macc = __builtin_amdgcn_mfma_f32_16x16x32_bf16(qpa.b, kpf, zz, 0, 0, 0);
#pragma unroll
      for (int r = 0; r < 4; r++) {
        float e = fexp2(macc[r]);                 // macc = 2*log2e*x
        float d = frcp(e + 1.f);
        float th = fmaf(d, -2.f * L2E_, L2E_);    // log2e*tanh(x)
        scp[nt][r] = sacc[r] + th;
      }
    }
    if (s0 + KT > L_) {   // tail masking
#pragma unroll
      for (int nt = 0; nt < 8; nt++) {
        if (s0 + nt * 16 + m >= L_) {
#pragma unroll
          for (int r = 0; r < 4; r++) scp[nt][r] = -3e38f;
        }
      }
    }

    // ---- online softmax in exp2 domain (registers only) ----
    float mnew[4], alpha[4];
#pragma unroll
    for (int r = 0; r < 4; r++) {
      float rm = scp[0][r];
#pragma unroll
      for (int nt = 1; nt < 8; nt++) rm = fmaxf(rm, scp[nt][r]);
#pragma unroll
      for (int msk = 1; msk < 16; msk <<= 1) rm = fmaxf(rm, __shfl_xor(rm, msk, 64));
      mnew[r] = fmaxf(mrun[r], rm);
      alpha[r] = fexp2(mrun[r] - mnew[r]);
      mrun[r] = mnew[r];
    }
    float rs[4] = {0.f, 0.f, 0.f, 0.f};
#pragma unroll
    for (int nt = 0; nt < 8; nt++)
#pragma unroll
      for (int r = 0; r < 4; r++) {
        float p = fexp2(scp[nt][r] - mnew[r]);
        scp[nt][r] = p;
        rs[r] += p;
      }
#pragma unroll
    for (int r = 0; r < 4; r++) {
#pragma unroll
      for (int msk = 1; msk < 16; msk <<= 1) rs[r] += __shfl_xor(rs[r], msk, 64);
      lrun[r] = lrun[r] * alpha[r] + rs[r];
    }
    f32x4 av = (f32x4){alpha[0], alpha[1], alpha[2], alpha[3]};
#pragma unroll
    for (int nt = 0; nt < 4; nt++) O[nt] *= av;

    __syncthreads();   // B3: all waves done reading Ks before P overwrites it

    // ---- P: C-layout -> per-wave LDS slice -> A-layout ----
#pragma unroll
    for (int nt = 0; nt < 8; nt++)
#pragma unroll
      for (int r = 0; r < 4; r++)
        pw[(quad * 4 + r) * LDP + nt * 16 + m] = f2bf(scp[nt][r]);

#pragma unroll
    for (int kc = 0; kc < 4; kc++) {
      bf16x8 pa = *(const bf16x8*)(pr0 + kc * 32);
#pragma unroll
      for (int nt = 0; nt < 4; nt++) {
        const u16* vb = Vt + (nt * 16 + m) * KT + (((kc * 4 + quad) ^ m) * 8);
        O[nt] = __builtin_amdgcn_mfma_f32_16x16x32_bf16(pa, *(const bf16x8*)vb, O[nt], 0, 0, 0);
      }
    }
  }

  float inv[4];
#pragma unroll
  for (int r = 0; r < 4; r++) inv[r] = frcp(lrun[r]);
#pragma unroll
  for (int r = 0; r < 4; r++) {
    int l = l0 + wv * 16 + quad * 4 + r;
    if (l >= L_) continue;
    u16* crow = ctx + ((size_t)(b * L_ + l)) * DM_ + hh * DK_;
#pragma unroll
    for (int nt = 0; nt < 4; nt++) crow[nt * 16 + m] = f2bf(O[nt][r] * inv[r]);
  }
}

// ---------------- layernorm -------------------------------------------------
__global__ __launch_bounds__(256)
void ln_kernel(const float* __restrict__ a, const float* __restrict__ badd,
               const float* __restrict__ g, const float* __restrict__ be,
               float* __restrict__ o, u16* __restrict__ o16) {
  int row = blockIdx.x;
  int t = threadIdx.x;
  size_t base = (size_t)row * DM_;
  float x0 = a[base + t], x1 = a[base + t + 256];
  if (badd) { x0 += badd[base + t]; x1 += badd[base + t + 256]; }
  float s = wave_reduce_sum(x0 + x1);
  float ss = wave_reduce_sum(x0 * x0 + x1 * x1);
  __shared__ float sh_s[4], sh_ss[4];
  int wv = t >> 6, lane = t & 63;
  if (lane == 0) { sh_s[wv] = s; sh_ss[wv] = ss; }
  __syncthreads();
  float S = sh_s[0] + sh_s[1] + sh_s[2] + sh_s[3];
  float SS = sh_ss[0] + sh_ss[1] + sh_ss[2] + sh_ss[3];
  float mean = S * (1.0f / DM_);
  float var = SS * (1.0f / DM_) - mean * mean;
  float rstd = rsqrtf(var + EPS_);
  float r0 = (x0 - mean) * rstd * g[t] + be[t];
  float r1 = (x1 - mean) * rstd * g[t + 256] + be[t + 256];
  o[base + t] = r0; o[base + t + 256] = r1;
  if (o16) { o16[base + t] = f2bf(r0); o16[base + t + 256] = f2bf(r1); }
}

// ---------------- fused double layernorm ------------------------------------
__global__ __launch_bounds__(256)
void ln2x_kernel(const float* __restrict__ hin, const float* __restrict__ y,
                 const float* __restrict__ g, const float* __restrict__ be,
                 float* __restrict__ o32, u16* __restrict__ o16) {
  int row = blockIdx.x;
  int t = threadIdx.x;
  size_t base = (size_t)row * DM_;
  float y0 = y[base + t], y1 = y[base + t + 256];
  float x0 = hin[base + t] + y0, x1 = hin[base + t + 256] + y1;
  __shared__ float sh_s[4], sh_ss[4];
  int wv = t >> 6, lane = t & 63;
  float g0 = g[t], g1v = g[t + 256], b0 = be[t], b1v = be[t + 256];

  float s = wave_reduce_sum(x0 + x1);
  float ss = wave_reduce_sum(x0 * x0 + x1 * x1);
  if (lane == 0) { sh_s[wv] = s; sh_ss[wv] = ss; }
  __syncthreads();
  float S = sh_s[0] + sh_s[1] + sh_s[2] + sh_s[3];
  float SS = sh_ss[0] + sh_ss[1] + sh_ss[2] + sh_ss[3];
  float mean = S * (1.0f / DM_);
  float var = SS * (1.0f / DM_) - mean * mean;
  float rstd = rsqrtf(var + EPS_);
  float h20 = (x0 - mean) * rstd * g0 + b0 + y0;
  float h21 = (x1 - mean) * rstd * g1v + b1v + y1;
  __syncthreads();

  s = wave_reduce_sum(h20 + h21);
  ss = wave_reduce_sum(h20 * h20 + h21 * h21);
  if (lane == 0) { sh_s[wv] = s; sh_ss[wv] = ss; }
  __syncthreads();
  S = sh_s[0] + sh_s[1] + sh_s[2] + sh_s[3];
  SS = sh_ss[0] + sh_ss[1] + sh_ss[2] + sh_ss[3];
  mean = S * (1.0f / DM_);
  var = SS * (1.0f / DM_) - mean * mean;
  rstd = rsqrtf(var + EPS_);
  float r0 = (h20 - mean) * rstd * g0 + b0;
  float r1 = (h21 - mean) * rstd * g1v + b1v;
  o32[base + t] = r0; o32[base + t + 256] = r1;
  if (o16) { o16[base + t] = f2bf(r0); o16[base + t + 256] = f2bf(r1); }
}

// ---------------- final head ------------------------------------------------
__global__ __launch_bounds__(512)
void final_kernel(const float* __restrict__ h, const float* __restrict__ gn,
                  const float* __restrict__ bn, const float* __restrict__ fcw,
                  const float* __restrict__ fcb, float* __restrict__ out) {
  int b = blockIdx.x;
  int t = threadIdx.x;
  size_t base = ((size_t)b * L_ + (L_ - 1)) * DM_;
  float x = h[base + t];
  float s = wave_reduce_sum(x);
  float ss = wave_reduce_sum(x * x);
  __shared__ float sh_s[8], sh_ss[8];
  int wv = t >> 6, lane = t & 63;
  if (lane == 0) { sh_s[wv] = s; sh_ss[wv] = ss; }
  __syncthreads();
  float S = 0.f, SS = 0.f;
#pragma unroll
  for (int i = 0; i < 8; i++) { S += sh_s[i]; SS += sh_ss[i]; }
  float mean = S * (1.0f / DM_);
  float var = SS * (1.0f / DM_) - mean * mean;
  float rstd = rsqrtf(var + EPS_);
  __shared__ float hn[DM_];
  hn[t] = (x - mean) * rstd * gn[t] + bn[t];
  __syncthreads();
  if (t < PRED_) {
    float acc = fcb[t];
#pragma unroll 8
    for (int d = 0; d < DM_; d++) acc = fmaf(hn[d], fcw[d * PRED_ + t], acc);
    out[b * PRED_ + t] = acc;
  }
}

// ---------------- driver ----------------
extern "C" void kernel_launch(void* const* d_in, const int* in_sizes, int n_in,
                              void* d_out, int out_size, void* d_ws, size_t ws_size,
                              hipStream_t stream) {
  const float* x     = (const float*)d_in[0];
  const float* emb_w = (const float*)d_in[1];
  const float* emb_b = (const float*)d_in[2];
  const float* pe    = (const float*)d_in[3];
  const float* Wq = (const float*)d_in[4];  const float* bq = (const float*)d_in[5];
  const float* Wk = (const float*)d_in[6];  const float* bk = (const float*)d_in[7];
  const float* Wv = (const float*)d_in[8];  const float* bv = (const float*)d_in[9];
  const float* Wo = (const float*)d_in[10]; const float* bo = (const float*)d_in[11];
  const float* W1 = (const float*)d_in[12]; const float* b1 = (const float*)d_in[13];
  const float* W2 = (const float*)d_in[14]; const float* b2 = (const float*)d_in[15];
  const float* g1 = (const float*)d_in[16]; const float* be1 = (const float*)d_in[17];
  const float* g2 = (const float*)d_in[18]; const float* be2 = (const float*)d_in[19];
  const float* lm_qw = (const float*)d_in[20]; const float* lm_qb = (const float*)d_in[21];
  const float* lm_kw = (const float*)d_in[22]; const float* lm_kb = (const float*)d_in[23];
  const float* gn = (const float*)d_in[24]; const float* bn = (const float*)d_in[25];
  const float* fc_w = (const float*)d_in[26]; const float* fc_b = (const float*)d_in[27];
  float* out = (float*)d_out;

  const size_t ROWS = (size_t)B_ * L_;     // 8000
  u16* qkv16 = (u16*)d_ws;                               // [8000][1536]
  u16* ctx16 = qkv16 + ROWS * QKVS;                      // [8000][512]
  u16* ffn1  = qkv16;                                    // [8000][2048] alias
  u16* h16   = ctx16 + ROWS * DM_;                       // [8000][512]
  u16* qp16  = h16 + ROWS * DM_;                         // [8000][128]
  u16* kp16  = qp16 + ROWS * H_ * P_;
  u16* Wqkv_t = kp16 + ROWS * H_ * P_;                   // [NL][1536][512]
  u16* Wo_t   = Wqkv_t + (size_t)NL_ * QKVS * DM_;       // [NL][512][512]
  u16* W1_t   = Wo_t + (size_t)NL_ * DM_ * DM_;          // [NL][2048][512]
  u16* W2_t   = W1_t + (size_t)NL_ * DFF_ * DM_;         // [NL][512][2048]
  float* h32  = (float*)(W2_t + (size_t)NL_ * DM_ * DFF_);
  float* t0   = h32 + ROWS * DM_;
  float* bqkv = t0 + ROWS * DM_;                         // [NL][1536]
  u16* vtg    = (u16*)t0;   // [64][64][1024] = 8.4 MB, aliases t0 (dead during attn)

  transpose_w<<<dim3(16, 16, NL_), 256, 0, stream>>>(Wq, Wqkv_t, DM_, DM_, (size_t)DM_ * DM_, (size_t)QKVS * DM_, 0, DM_);
  transpose_w<<<dim3(16, 16, NL_), 256, 0, stream>>>(Wk, Wqkv_t, DM_, DM_, (size_t)DM_ * DM_, (size_t)QKVS * DM_, 512, DM_);
  transpose_w<<<dim3(16, 16, NL_), 256, 0, stream>>>(Wv, Wqkv_t, DM_, DM_, (size_t)DM_ * DM_, (size_t)QKVS * DM_, 1024, DM_);
  transpose_w<<<dim3(16, 16, NL_), 256, 0, stream>>>(Wo, Wo_t, DM_, DM_, (size_t)DM_ * DM_, (size_t)DM_ * DM_, 0, DM_);
  transpose_w<<<dim3(64, 16, NL_), 256, 0, stream>>>(W1, W1_t, DM_, DFF_, (size_t)DM_ * DFF_, (size_t)DFF_ * DM_, 0, DM_);
  transpose_w<<<dim3(16, 64, NL_), 256, 0, stream>>>(W2, W2_t, DFF_, DM_, (size_t)DFF_ * DM_, (size_t)DM_ * DFF_, 0, DFF_);
  concat_bias<<<NL_ * QKVS / 256, 256, 0, stream>>>(bq, bk, bv, bqkv);

  embed_kernel<<<dim3((unsigned)ROWS), 512, 0, stream>>>(x, emb_w, emb_b, pe, h32, h16);

  dim3 g_qkv(QKVS / 128, 63);
  dim3 g_ffn1(DFF_ / 128, 63);
  dim3 g_n512(DM_ / 64, 63);
  dim3 g_attn(16, B_ * H_);
  dim3 g_lm((unsigned)ROWS, 2);

  for (int i = 0; i < NL_; i++) {
    gemm16<128><<<g_qkv, 256, 0, stream>>>(h16, Wqkv_t + (size_t)i * QKVS * DM_,
        bqkv + i * QKVS, nullptr, nullptr, qkv16, 8000, DM_, QKVS, 0, 512, C_QS);

    lmproj_kernel<<<g_lm, 128, 0, stream>>>(qkv16, lm_qw, lm_qb, lm_kw, lm_kb, qp16, kp16);
    vtrans_kernel<<<dim3(32, 2, B_ * H_), 256, 0, stream>>>(qkv16, vtg);

    attn_mfma_kernel<<<g_attn, 256, 0, stream>>>(qkv16, qp16, kp16, vtg, ctx16);

    gemm16<64><<<g_n512, 256, 0, stream>>>(ctx16, Wo_t + (size_t)i * DM_ * DM_,
        bo + i * DM_, h32, t0, nullptr, 8000, DM_, DM_, 0, 0, 1.0f);
    ln_kernel<<<dim3((unsigned)ROWS), 256, 0, stream>>>(t0, nullptr, g1 + i * DM_, be1 + i * DM_, h32, h16);

    gemm16<128><<<g_ffn1, 256, 0, stream>>>(h16, W1_t + (size_t)i * DFF_ * DM_,
        b1 + i * DFF_, nullptr, nullptr, ffn1, 8000, DM_, DFF_, 1, 0, 1.0f);
    gemm16<64><<<g_n512, 256, 0, stream>>>(ffn1, W2_t + (size_t)i * DM_ * DFF_,
        b2 + i * DM_, nullptr, t0, nullptr, 8000, DFF_, DM_, 0, 0, 1.0f);

    ln2x_kernel<<<dim3((unsigned)ROWS), 256, 0, stream>>>(h32, t0, g2 + i * DM_, be2 + i * DM_, h32, h16);
  }

  final_kernel<<<B_, 512, 0, stream>>>(h32, gn, bn, fc_w, fc_b, out);
}

// Round 7
// 1260.226 us; speedup vs baseline: 1.2848x; 1.0555x over previous
//
#include <hip/hip_runtime.h>
#include <math.h>

// Problem constants (PCUTransformer)
#define B_    8
#define L_    1000
#define F_    7
#define DM_   512
#define H_    8
#define DFF_  2048
#define NL_   4
#define PRED_ 50
#define DK_   64
#define P_    16
#define EPS_  1e-5f
#define QKVS  1536      // fused qkv row stride

#define L2E_   1.4426950408889634f
#define C_QS   0.18033688011112042f   // 0.125 * log2(e) folded into q
#define WS_QP  16.0f                  // lmproj-q weight compensation: 16*C_QS = 2*log2e
#define BS_QP  2.8853900817779268f    // 2*log2(e) bias scale
#define SHFT_  24.0f                  // fixed softmax shift (cancels in normalize)

typedef unsigned short u16;
typedef __bf16 bf16x8 __attribute__((ext_vector_type(8)));
typedef float  f32x4  __attribute__((ext_vector_type(4)));

// ---------------- helpers ----------------
__device__ inline float wave_reduce_sum(float x) {
#pragma unroll
  for (int off = 32; off >= 1; off >>= 1) x += __shfl_xor(x, off, 64);
  return x;
}
__device__ inline u16 f2bf(float f) {   // RNE float->bf16 bits
  unsigned int u = __float_as_uint(f);
  unsigned int r = u + 0x7FFFu + ((u >> 16) & 1u);
  return (u16)(r >> 16);
}
__device__ inline float bf2f(u16 u) { return __uint_as_float(((unsigned int)u) << 16); }
__device__ inline float fexp2(float x) { return __builtin_amdgcn_exp2f(x); }
__device__ inline float frcp(float x) { return __builtin_amdgcn_rcpf(x); }

union bfrag { bf16x8 b; uint4 q; u16 u[8]; };

// async global->LDS, 16B per lane; lds base wave-uniform, HW scatters lane*16
__device__ inline void gload16(const u16* g, u16* l) {
  __builtin_amdgcn_global_load_lds(
      (const __attribute__((address_space(1))) void*)g,
      (__attribute__((address_space(3))) void*)l, 16, 0, 0);
}

// ---------------- weight transpose-convert: out[n][k] = bf16(in[k][n]) ------
__global__ __launch_bounds__(256)
void transpose_w(const float* __restrict__ in, u16* __restrict__ out,
                 int K, int N, size_t in_lstride, size_t out_lstride,
                 int row_off, int out_ld) {
  __shared__ float tile[32][33];
  int z = blockIdx.z;
  int kk0 = blockIdx.y * 32, nn0 = blockIdx.x * 32;
  int tx = threadIdx.x & 31, ty = threadIdx.x >> 5;
  const float* ip = in + z * in_lstride;
  u16* op = out + z * out_lstride;
#pragma unroll
  for (int i = 0; i < 4; i++)
    tile[ty + i * 8][tx] = ip[(size_t)(kk0 + ty + i * 8) * N + nn0 + tx];
  __syncthreads();
#pragma unroll
  for (int i = 0; i < 4; i++)
    op[(size_t)(row_off + nn0 + ty + i * 8) * out_ld + kk0 + tx] = f2bf(tile[tx][ty + i * 8]);
}

// ---------------- V transpose: vt[b*8+h][dk][key(1024 pad)] = v -------------
__global__ __launch_bounds__(256)
void vtrans_kernel(const u16* __restrict__ qkv, u16* __restrict__ vtg) {
  __shared__ u16 tile[32][33];
  int bh = blockIdx.z;
  int b = bh >> 3, hh = bh & 7;
  int k0 = blockIdx.x * 32;   // key
  int d0 = blockIdx.y * 32;   // dk
  int tx = threadIdx.x & 31, ty = threadIdx.x >> 5;
#pragma unroll
  for (int i = 0; i < 4; i++) {
    int key = k0 + ty + i * 8;
    u16 v = 0;
    if (key < L_) v = qkv[(size_t)(b * L_ + key) * QKVS + 1024 + hh * DK_ + d0 + tx];
    tile[ty + i * 8][tx] = v;
  }
  __syncthreads();
#pragma unroll
  for (int i = 0; i < 4; i++)
    vtg[((size_t)bh * DK_ + d0 + ty + i * 8) * 1024 + k0 + tx] = tile[tx][ty + i * 8];
}

// ---------------- qkv bias concat -------------------------------------------
__global__ __launch_bounds__(256)
void concat_bias(const float* __restrict__ bq, const float* __restrict__ bk,
                 const float* __restrict__ bv, float* __restrict__ bqkv) {
  int i = blockIdx.x * 256 + threadIdx.x;
  int l = i / QKVS, j = i % QKVS;
  float v = (j < 512) ? bq[l * 512 + j] : (j < 1024) ? bk[l * 512 + j - 512]
                                                     : bv[l * 512 + j - 1024];
  bqkv[i] = v;
}

// ---------------- embedding -------------------------------------------------
__global__ __launch_bounds__(512)
void embed_kernel(const float* __restrict__ x, const float* __restrict__ emb_w,
                  const float* __restrict__ emb_b, const float* __restrict__ pe,
                  float* __restrict__ h, u16* __restrict__ h16) {
  int bl = blockIdx.x;
  int l = bl % L_;
  int d = threadIdx.x;
  const float* xr = x + (size_t)bl * F_;
  float acc = emb_b[d] + pe[(size_t)l * DM_ + d];
#pragma unroll
  for (int f = 0; f < F_; f++) acc = fmaf(xr[f], emb_w[f * DM_ + d], acc);
  h[(size_t)bl * DM_ + d] = acc;
  h16[(size_t)bl * DM_ + d] = f2bf(acc);
}

// ---------------- bf16 MFMA GEMM, BK=64 (half the barrier drains) -----------
// LDS rows of 64 elems, 8-chunk XOR swizzle (slot s holds chunk s^(row&7)).
template<int BN>
__global__ __launch_bounds__(256)
void gemm16(const u16* __restrict__ A, const u16* __restrict__ Bt,
            const float* __restrict__ bias, const float* __restrict__ resid,
            float* __restrict__ C32, u16* __restrict__ C16,
            int M, int K, int N, int relu, int nscale, float sval) {
  constexpr int NTW = BN / 32;   // n-tiles of 16 per wave
  constexpr int BG  = BN / 32;   // B gloads per wave (8 rows each)
  __shared__ u16 As[128 * 64];
  __shared__ u16 Bs[BN * 64];
  int t = threadIdx.x;
  int w = t >> 6, lane = t & 63;
  int wr = w >> 1, wc = w & 1;
  int mloc = lane & 15, quad = lane >> 4;
  int m0 = blockIdx.y * 128, n0 = blockIdx.x * BN;

  // staging: each gload16 covers 8 rows x 64 elems; lane = (row<<3)|slot
  const u16* agp[4]; u16* alds[4];
#pragma unroll
  for (int j = 0; j < 4; j++) {
    int r = w * 32 + j * 8 + (lane >> 3);
    int gm = m0 + r; if (gm > M - 1) gm = M - 1;
    int ch = (lane & 7) ^ (r & 7);
    agp[j] = A + (size_t)gm * K + ch * 8;
    alds[j] = As + (w * 32 + j * 8) * 64;
  }
  const u16* bgp[BG]; u16* blds[BG];
#pragma unroll
  for (int j = 0; j < BG; j++) {
    int r = w * (8 * BG) + j * 8 + (lane >> 3);
    int ch = (lane & 7) ^ (r & 7);
    bgp[j] = Bt + (size_t)(n0 + r) * K + ch * 8;
    blds[j] = Bs + (w * (8 * BG) + j * 8) * 64;
  }
  // fragment pointers: k-chunk c = kc*4+quad, slot = c ^ (row&7)
  const u16* apt[2][4];
#pragma unroll
  for (int mi = 0; mi < 4; mi++) {
    int tr = wr * 64 + mi * 16 + mloc;
    apt[0][mi] = As + tr * 64 + ((quad ^ (tr & 7)) * 8);
    apt[1][mi] = As + tr * 64 + (((4 + quad) ^ (tr & 7)) * 8);
  }
  const u16* bpt[2][NTW];
#pragma unroll
  for (int nt = 0; nt < NTW; nt++) {
    int tr = wc * (BN / 2) + nt * 16 + mloc;
    bpt[0][nt] = Bs + tr * 64 + ((quad ^ (tr & 7)) * 8);
    bpt[1][nt] = Bs + tr * 64 + (((4 + quad) ^ (tr & 7)) * 8);
  }

  f32x4 acc[4][NTW];
#pragma unroll
  for (int mi = 0; mi < 4; mi++)
#pragma unroll
    for (int nt = 0; nt < NTW; nt++) acc[mi][nt] = (f32x4){0.f, 0.f, 0.f, 0.f};

  for (int k0 = 0; k0 < K; k0 += 64) {
    __syncthreads();
    #pragma unroll
    for (int j = 0; j < 4; j++) gload16(agp[j] + k0, alds[j]);
    #pragma unroll
    for (int j = 0; j < BG; j++) gload16(bgp[j] + k0, blds[j]);
    __syncthreads();
#pragma unroll
    for (int kc = 0; kc < 2; kc++) {
      bf16x8 af[4], bv[NTW];
#pragma unroll
      for (int mi = 0; mi < 4; mi++) af[mi] = *(const bf16x8*)apt[kc][mi];
#pragma unroll
      for (int nt = 0; nt < NTW; nt++) bv[nt] = *(const bf16x8*)bpt[kc][nt];
#pragma unroll
      for (int mi = 0; mi < 4; mi++)
#pragma unroll
        for (int nt = 0; nt < NTW; nt++)
          acc[mi][nt] = __builtin_amdgcn_mfma_f32_16x16x32_bf16(af[mi], bv[nt], acc[mi][nt], 0, 0, 0);
    }
  }

#pragma unroll
  for (int mi = 0; mi < 4; mi++) {
#pragma unroll
    for (int r = 0; r < 4; r++) {
      int m = m0 + wr * 64 + mi * 16 + quad * 4 + r;
      if (m >= M) continue;
      size_t crow = (size_t)m * N;
#pragma unroll
      for (int nt = 0; nt < NTW; nt++) {
        int n = n0 + wc * (BN / 2) + nt * 16 + mloc;
        float vsum = acc[mi][nt][r] + bias[n];
        if (resid) vsum += resid[crow + n];
        if (n < nscale) vsum *= sval;
        if (relu) vsum = fmaxf(vsum, 0.f);
        if (C32) C32[crow + n] = vsum;
        if (C16) C16[crow + n] = f2bf(vsum);
      }
    }
  }
}

// ---------------- fused learned-mask projection (q and k in one launch) -----
__global__ __launch_bounds__(128)
void lmproj_kernel(const u16* __restrict__ qkv,
                   const float* __restrict__ wq, const float* __restrict__ bq,
                   const float* __restrict__ wk, const float* __restrict__ bk,
                   u16* __restrict__ qp, u16* __restrict__ kp) {
  int bl = blockIdx.x;
  int which = blockIdx.y;            // 0 = q (scaled), 1 = k
  int t = threadIdx.x;
  int hh = t >> 4, p = t & 15;
  const float* w  = which ? wk : wq;
  const float* bb = which ? bk : bq;
  u16* dst        = which ? kp : qp;
  float wscale = which ? 1.0f : WS_QP;
  float bscale = which ? 1.0f : BS_QP;
  const u16* s = qkv + (size_t)bl * QKVS + (which ? 512 : 0) + hh * DK_;
  float acc = 0.f;
#pragma unroll
  for (int d = 0; d < DK_; d++) acc = fmaf(bf2f(s[d]), w[d * P_ + p], acc);
  dst[((size_t)bl * H_ + hh) * P_ + p] = f2bf(fmaf(acc, wscale, bb[p] * bscale));
}

// ---------------- MFMA flash attention: fixed-shift softmax, Ps aliases Ks --
// No online max: p = exp2(score - 24) (constant cancels in the final
// normalize; scores are O(+-10) in log2 domain, far from exp2 overflow).
#define KT   128
#define LDP  136   // Ps row stride (272B = 17*16B)
#define KPLD 24    // Kp row stride (48B)
__global__ __launch_bounds__(256)
void attn_mfma_kernel(const u16* __restrict__ qkv, const u16* __restrict__ qpg,
                      const u16* __restrict__ kpg, const u16* __restrict__ vtg,
                      u16* __restrict__ ctx) {
  __shared__ u16 KsPs[4 * 16 * LDP];   // 17408B; Ks view = first 128*64 elems
  __shared__ u16 Vt[64 * KT];          // 16384B  [dk][key], XOR-swizzled
  __shared__ u16 Kp[KT * KPLD];        // 6144B   [key][p 0..15]

  // XCD swizzle: all 16 q-tiles of one (b,h) share linear%8 -> same XCD L2
  int Lid = blockIdx.x;                // 0..1023
  int qt = Lid >> 6;
  int bh = ((Lid & 7) << 3) | ((Lid >> 3) & 7);
  int b = bh >> 3, hh = bh & 7;
  int l0 = qt * 64;
  int t = threadIdx.x;
  int wv = t >> 6, lane = t & 63;
  int m = lane & 15, quad = lane >> 4;

  // Q (pre-scaled by 0.125*log2e in GEMM) + qp (pre-scaled by 2*log2e)
  int lq = l0 + wv * 16 + m; if (lq > L_ - 1) lq = L_ - 1;
  const u16* qrow = qkv + (size_t)(b * L_ + lq) * QKVS + hh * DK_;
  bf16x8 qa0 = *(const bf16x8*)(qrow + quad * 8);
  bf16x8 qa1 = *(const bf16x8*)(qrow + 32 + quad * 8);
  bfrag qpa;
  if (quad < 2) {
    qpa.q = *(const uint4*)(qpg + ((size_t)(b * L_ + lq) * H_ + hh) * P_ + quad * 8);
  } else {
    qpa.q = make_uint4(0u, 0u, 0u, 0u);
  }

  // staging addresses: slot s of row r holds chunk s^(r&7) (r&15 for Vt)
  const u16* ks_g = qkv + ((size_t)b * L_ + (t >> 3)) * QKVS + 512 + hh * DK_
                    + ((t & 7) ^ ((t >> 3) & 7)) * 8;
  u16* ks_l = KsPs + (t >> 6) * 512;
  const u16* vt_g = vtg + ((size_t)bh * DK_ + (t >> 4)) * 1024
                    + (((t & 15) ^ (t >> 4)) * 8);
  u16* vt_l = Vt + (t >> 6) * 512;

  f32x4 O[4];
#pragma unroll
  for (int nt = 0; nt < 4; nt++) O[nt] = (f32x4){0.f, 0.f, 0.f, 0.f};
  float lrun[4] = {0.f, 0.f, 0.f, 0.f};

  u16* pw = KsPs + wv * (16 * LDP);
  const u16* pr0 = pw + m * LDP + quad * 8;

  for (int s0 = 0; s0 < L_; s0 += KT) {
    uint4 p0, p1;
    if (t < KT) {
      int sg2 = s0 + t; if (sg2 > L_ - 1) sg2 = L_ - 1;
      const u16* pr = kpg + ((size_t)(b * L_ + sg2) * H_ + hh) * P_;
      p0 = *(const uint4*)(pr);
      p1 = *(const uint4*)(pr + 8);
    }
    __syncthreads();   // B1: prev Ps/Vt/Kp reads done
#pragma unroll
    for (int j = 0; j < 4; j++) {
      gload16(ks_g + ((size_t)s0 + j * 32) * QKVS, ks_l + j * 2048);
      gload16(vt_g + s0 + (size_t)j * 16 * 1024, vt_l + j * 2048);
    }
    if (t < KT) {
      *(uint4*)&Kp[t * KPLD]     = p0;
      *(uint4*)&Kp[t * KPLD + 8] = p1;
    }
    __syncthreads();   // B2: tile staged

    // ---- scores -> p = exp2(score - SHFT_) directly ----
    float scp[8][4];
    const f32x4 zz = (f32x4){0.f, 0.f, 0.f, 0.f};
#pragma unroll
    for (int nt = 0; nt < 8; nt++) {
      const u16* kb = KsPs + (nt * 16 + m) * 64;
      int x0 = ((quad) ^ (m & 7)) * 8;
      int x1 = ((4 + quad) ^ (m & 7)) * 8;
      f32x4 sacc = __builtin_amdgcn_mfma_f32_16x16x32_bf16(qa0, *(const bf16x8*)(kb + x0), zz, 0, 0, 0);
      sacc = __builtin_amdgcn_mfma_f32_16x16x32_bf16(qa1, *(const bf16x8*)(kb + x1), sacc, 0, 0, 0);
      bf16x8 kpf = *(const bf16x8*)(Kp + (nt * 16 + m) * KPLD + (quad & 1) * 8);
      f32x4 macc = __builtin_amdgcn_mfma_f32_16x16x32_bf16(qpa.b, kpf, zz, 0, 0, 0);
#pragma unroll
      for (int r = 0; r < 4; r++) {
        float e = fexp2(macc[r]);                 // macc = 2*log2e*x
        float d = frcp(e + 1.f);
        float th = fmaf(d, -2.f * L2E_, L2E_);    // log2e*tanh(x)
        scp[nt][r] = sacc[r] + th;
      }
    }
    if (s0 + KT > L_) {   // tail masking
#pragma unroll
      for (int nt = 0; nt < 8; nt++) {
        if (s0 + nt * 16 + m >= L_) {
#pragma unroll
          for (int r = 0; r < 4; r++) scp[nt][r] = -3e38f;
        }
      }
    }
#pragma unroll
    for (int nt = 0; nt < 8; nt++)
#pragma unroll
      for (int r = 0; r < 4; r++) {
        float p = fexp2(scp[nt][r] - SHFT_);      // exp2(-3e38)=0 for masked
        scp[nt][r] = p;
        lrun[r] += p;                              // per-lane partial sum
      }

    __syncthreads();   // B3: all waves done reading Ks before P overwrites it

    // ---- P: C-layout -> per-wave LDS slice -> A-layout ----
#pragma unroll
    for (int nt = 0; nt < 8; nt++)
#pragma unroll
      for (int r = 0; r < 4; r++)
        pw[(quad * 4 + r) * LDP + nt * 16 + m] = f2bf(scp[nt][r]);

#pragma unroll
    for (int kc = 0; kc < 4; kc++) {
      bf16x8 pa = *(const bf16x8*)(pr0 + kc * 32);
#pragma unroll
      for (int nt = 0; nt < 4; nt++) {
        const u16* vb = Vt + (nt * 16 + m) * KT + (((kc * 4 + quad) ^ m) * 8);
        O[nt] = __builtin_amdgcn_mfma_f32_16x16x32_bf16(pa, *(const bf16x8*)vb, O[nt], 0, 0, 0);
      }
    }
  }

  // single end-of-kernel row-sum reduction + normalize
  float inv[4];
#pragma unroll
  for (int r = 0; r < 4; r++) {
#pragma unroll
    for (int msk = 1; msk < 16; msk <<= 1) lrun[r] += __shfl_xor(lrun[r], msk, 64);
    inv[r] = frcp(lrun[r]);
  }
#pragma unroll
  for (int r = 0; r < 4; r++) {
    int l = l0 + wv * 16 + quad * 4 + r;
    if (l >= L_) continue;
    u16* crow = ctx + ((size_t)(b * L_ + l)) * DM_ + hh * DK_;
#pragma unroll
    for (int nt = 0; nt < 4; nt++) crow[nt * 16 + m] = f2bf(O[nt][r] * inv[r]);
  }
}

// ---------------- layernorm -------------------------------------------------
__global__ __launch_bounds__(256)
void ln_kernel(const float* __restrict__ a, const float* __restrict__ badd,
               const float* __restrict__ g, const float* __restrict__ be,
               float* __restrict__ o, u16* __restrict__ o16) {
  int row = blockIdx.x;
  int t = threadIdx.x;
  size_t base = (size_t)row * DM_;
  float x0 = a[base + t], x1 = a[base + t + 256];
  if (badd) { x0 += badd[base + t]; x1 += badd[base + t + 256]; }
  float s = wave_reduce_sum(x0 + x1);
  float ss = wave_reduce_sum(x0 * x0 + x1 * x1);
  __shared__ float sh_s[4], sh_ss[4];
  int wv = t >> 6, lane = t & 63;
  if (lane == 0) { sh_s[wv] = s; sh_ss[wv] = ss; }
  __syncthreads();
  float S = sh_s[0] + sh_s[1] + sh_s[2] + sh_s[3];
  float SS = sh_ss[0] + sh_ss[1] + sh_ss[2] + sh_ss[3];
  float mean = S * (1.0f / DM_);
  float var = SS * (1.0f / DM_) - mean * mean;
  float rstd = rsqrtf(var + EPS_);
  float r0 = (x0 - mean) * rstd * g[t] + be[t];
  float r1 = (x1 - mean) * rstd * g[t + 256] + be[t + 256];
  o[base + t] = r0; o[base + t + 256] = r1;
  if (o16) { o16[base + t] = f2bf(r0); o16[base + t + 256] = f2bf(r1); }
}

// ---------------- fused double layernorm ------------------------------------
__global__ __launch_bounds__(256)
void ln2x_kernel(const float* __restrict__ hin, const float* __restrict__ y,
                 const float* __restrict__ g, const float* __restrict__ be,
                 float* __restrict__ o32, u16* __restrict__ o16) {
  int row = blockIdx.x;
  int t = threadIdx.x;
  size_t base = (size_t)row * DM_;
  float y0 = y[base + t], y1 = y[base + t + 256];
  float x0 = hin[base + t] + y0, x1 = hin[base + t + 256] + y1;
  __shared__ float sh_s[4], sh_ss[4];
  int wv = t >> 6, lane = t & 63;
  float g0 = g[t], g1v = g[t + 256], b0 = be[t], b1v = be[t + 256];

  float s = wave_reduce_sum(x0 + x1);
  float ss = wave_reduce_sum(x0 * x0 + x1 * x1);
  if (lane == 0) { sh_s[wv] = s; sh_ss[wv] = ss; }
  __syncthreads();
  float S = sh_s[0] + sh_s[1] + sh_s[2] + sh_s[3];
  float SS = sh_ss[0] + sh_ss[1] + sh_ss[2] + sh_ss[3];
  float mean = S * (1.0f / DM_);
  float var = SS * (1.0f / DM_) - mean * mean;
  float rstd = rsqrtf(var + EPS_);
  float h20 = (x0 - mean) * rstd * g0 + b0 + y0;
  float h21 = (x1 - mean) * rstd * g1v + b1v + y1;
  __syncthreads();

  s = wave_reduce_sum(h20 + h21);
  ss = wave_reduce_sum(h20 * h20 + h21 * h21);
  if (lane == 0) { sh_s[wv] = s; sh_ss[wv] = ss; }
  __syncthreads();
  S = sh_s[0] + sh_s[1] + sh_s[2] + sh_s[3];
  SS = sh_ss[0] + sh_ss[1] + sh_ss[2] + sh_ss[3];
  mean = S * (1.0f / DM_);
  var = SS * (1.0f / DM_) - mean * mean;
  rstd = rsqrtf(var + EPS_);
  float r0 = (h20 - mean) * rstd * g0 + b0;
  float r1 = (h21 - mean) * rstd * g1v + b1v;
  o32[base + t] = r0; o32[base + t + 256] = r1;
  if (o16) { o16[base + t] = f2bf(r0); o16[base + t + 256] = f2bf(r1); }
}

// ---------------- final head ------------------------------------------------
__global__ __launch_bounds__(512)
void final_kernel(const float* __restrict__ h, const float* __restrict__ gn,
                  const float* __restrict__ bn, const float* __restrict__ fcw,
                  const float* __restrict__ fcb, float* __restrict__ out) {
  int b = blockIdx.x;
  int t = threadIdx.x;
  size_t base = ((size_t)b * L_ + (L_ - 1)) * DM_;
  float x = h[base + t];
  float s = wave_reduce_sum(x);
  float ss = wave_reduce_sum(x * x);
  __shared__ float sh_s[8], sh_ss[8];
  int wv = t >> 6, lane = t & 63;
  if (lane == 0) { sh_s[wv] = s; sh_ss[wv] = ss; }
  __syncthreads();
  float S = 0.f, SS = 0.f;
#pragma unroll
  for (int i = 0; i < 8; i++) { S += sh_s[i]; SS += sh_ss[i]; }
  float mean = S * (1.0f / DM_);
  float var = SS * (1.0f / DM_) - mean * mean;
  float rstd = rsqrtf(var + EPS_);
  __shared__ float hn[DM_];
  hn[t] = (x - mean) * rstd * gn[t] + bn[t];
  __syncthreads();
  if (t < PRED_) {
    float acc = fcb[t];
#pragma unroll 8
    for (int d = 0; d < DM_; d++) acc = fmaf(hn[d], fcw[d * PRED_ + t], acc);
    out[b * PRED_ + t] = acc;
  }
}

// ---------------- driver ----------------
extern "C" void kernel_launch(void* const* d_in, const int* in_sizes, int n_in,
                              void* d_out, int out_size, void* d_ws, size_t ws_size,
                              hipStream_t stream) {
  const float* x     = (const float*)d_in[0];
  const float* emb_w = (const float*)d_in[1];
  const float* emb_b = (const float*)d_in[2];
  const float* pe    = (const float*)d_in[3];
  const float* Wq = (const float*)d_in[4];  const float* bq = (const float*)d_in[5];
  const float* Wk = (const float*)d_in[6];  const float* bk = (const float*)d_in[7];
  const float* Wv = (const float*)d_in[8];  const float* bv = (const float*)d_in[9];
  const float* Wo = (const float*)d_in[10]; const float* bo = (const float*)d_in[11];
  const float* W1 = (const float*)d_in[12]; const float* b1 = (const float*)d_in[13];
  const float* W2 = (const float*)d_in[14]; const float* b2 = (const float*)d_in[15];
  const float* g1 = (const float*)d_in[16]; const float* be1 = (const float*)d_in[17];
  const float* g2 = (const float*)d_in[18]; const float* be2 = (const float*)d_in[19];
  const float* lm_qw = (const float*)d_in[20]; const float* lm_qb = (const float*)d_in[21];
  const float* lm_kw = (const float*)d_in[22]; const float* lm_kb = (const float*)d_in[23];
  const float* gn = (const float*)d_in[24]; const float* bn = (const float*)d_in[25];
  const float* fc_w = (const float*)d_in[26]; const float* fc_b = (const float*)d_in[27];
  float* out = (float*)d_out;

  const size_t ROWS = (size_t)B_ * L_;     // 8000
  u16* qkv16 = (u16*)d_ws;                               // [8000][1536]
  u16* ctx16 = qkv16 + ROWS * QKVS;                      // [8000][512]
  u16* ffn1  = qkv16;                                    // [8000][2048] alias
  u16* h16   = ctx16 + ROWS * DM_;                       // [8000][512]
  u16* qp16  = h16 + ROWS * DM_;                         // [8000][128]
  u16* kp16  = qp16 + ROWS * H_ * P_;
  u16* Wqkv_t = kp16 + ROWS * H_ * P_;                   // [NL][1536][512]
  u16* Wo_t   = Wqkv_t + (size_t)NL_ * QKVS * DM_;       // [NL][512][512]
  u16* W1_t   = Wo_t + (size_t)NL_ * DM_ * DM_;          // [NL][2048][512]
  u16* W2_t   = W1_t + (size_t)NL_ * DFF_ * DM_;         // [NL][512][2048]
  float* h32  = (float*)(W2_t + (size_t)NL_ * DM_ * DFF_);
  float* t0   = h32 + ROWS * DM_;
  float* bqkv = t0 + ROWS * DM_;                         // [NL][1536]
  u16* vtg    = (u16*)t0;   // [64][64][1024] = 8.4 MB, aliases t0 (dead during attn)

  transpose_w<<<dim3(16, 16, NL_), 256, 0, stream>>>(Wq, Wqkv_t, DM_, DM_, (size_t)DM_ * DM_, (size_t)QKVS * DM_, 0, DM_);
  transpose_w<<<dim3(16, 16, NL_), 256, 0, stream>>>(Wk, Wqkv_t, DM_, DM_, (size_t)DM_ * DM_, (size_t)QKVS * DM_, 512, DM_);
  transpose_w<<<dim3(16, 16, NL_), 256, 0, stream>>>(Wv, Wqkv_t, DM_, DM_, (size_t)DM_ * DM_, (size_t)QKVS * DM_, 1024, DM_);
  transpose_w<<<dim3(16, 16, NL_), 256, 0, stream>>>(Wo, Wo_t, DM_, DM_, (size_t)DM_ * DM_, (size_t)DM_ * DM_, 0, DM_);
  transpose_w<<<dim3(64, 16, NL_), 256, 0, stream>>>(W1, W1_t, DM_, DFF_, (size_t)DM_ * DFF_, (size_t)DFF_ * DM_, 0, DM_);
  transpose_w<<<dim3(16, 64, NL_), 256, 0, stream>>>(W2, W2_t, DFF_, DM_, (size_t)DFF_ * DM_, (size_t)DM_ * DFF_, 0, DFF_);
  concat_bias<<<NL_ * QKVS / 256, 256, 0, stream>>>(bq, bk, bv, bqkv);

  embed_kernel<<<dim3((unsigned)ROWS), 512, 0, stream>>>(x, emb_w, emb_b, pe, h32, h16);

  dim3 g_qkv(QKVS / 128, 63);
  dim3 g_ffn1(DFF_ / 128, 63);
  dim3 g_n512(DM_ / 64, 63);
  dim3 g_attn(1024);
  dim3 g_lm((unsigned)ROWS, 2);

  for (int i = 0; i < NL_; i++) {
    gemm16<128><<<g_qkv, 256, 0, stream>>>(h16, Wqkv_t + (size_t)i * QKVS * DM_,
        bqkv + i * QKVS, nullptr, nullptr, qkv16, 8000, DM_, QKVS, 0, 512, C_QS);

    lmproj_kernel<<<g_lm, 128, 0, stream>>>(qkv16, lm_qw, lm_qb, lm_kw, lm_kb, qp16, kp16);
    vtrans_kernel<<<dim3(32, 2, B_ * H_), 256, 0, stream>>>(qkv16, vtg);

    attn_mfma_kernel<<<g_attn, 256, 0, stream>>>(qkv16, qp16, kp16, vtg, ctx16);

    gemm16<64><<<g_n512, 256, 0, stream>>>(ctx16, Wo_t + (size_t)i * DM_ * DM_,
        bo + i * DM_, h32, t0, nullptr, 8000, DM_, DM_, 0, 0, 1.0f);
    ln_kernel<<<dim3((unsigned)ROWS), 256, 0, stream>>>(t0, nullptr, g1 + i * DM_, be1 + i * DM_, h32, h16);

    gemm16<128><<<g_ffn1, 256, 0, stream>>>(h16, W1_t + (size_t)i * DFF_ * DM_,
        b1 + i * DFF_, nullptr, nullptr, ffn1, 8000, DM_, DFF_, 1, 0, 1.0f);
    gemm16<64><<<g_n512, 256, 0, stream>>>(ffn1, W2_t + (size_t)i * DM_ * DFF_,
        b2 + i * DM_, nullptr, t0, nullptr, 8000, DFF_, DM_, 0, 0, 1.0f);

    ln2x_kernel<<<dim3((unsigned)ROWS), 256, 0, stream>>>(h32, t0, g2 + i * DM_, be2 + i * DM_, h32, h16);
  }

  final_kernel<<<B_, 512, 0, stream>>>(h32, gn, bn, fc_w, fc_b, out);
}

// Round 9
// 1223.184 us; speedup vs baseline: 1.3237x; 1.0303x over previous
//
#include <hip/hip_runtime.h>
#include <math.h>

// Problem constants (PCUTransformer)
#define B_    8
#define L_    1000
#define F_    7
#define DM_   512
#define H_    8
#define DFF_  2048
#define NL_   4
#define PRED_ 50
#define DK_   64
#define P_    16
#define EPS_  1e-5f
#define QKVS  1792      // fused row: q(512) k(512) v-gap(512) qp(128) kp(128)

#define L2E_   1.4426950408889634f
#define C_QS   0.18033688011112042f   // 0.125 * log2(e) folded into q
#define BS_QP  2.8853900817779268f    // 2*log2(e) folded into fused qp weights
#define SHFT_  24.0f                  // fixed softmax shift (cancels in normalize)

typedef unsigned short u16;
typedef __bf16 bf16x8 __attribute__((ext_vector_type(8)));
typedef float  f32x4  __attribute__((ext_vector_type(4)));

// ---------------- helpers ----------------
__device__ inline float wave_reduce_sum(float x) {
#pragma unroll
  for (int off = 32; off >= 1; off >>= 1) x += __shfl_xor(x, off, 64);
  return x;
}
__device__ inline u16 f2bf(float f) {   // RNE float->bf16 bits
  unsigned int u = __float_as_uint(f);
  unsigned int r = u + 0x7FFFu + ((u >> 16) & 1u);
  return (u16)(r >> 16);
}
__device__ inline float bf2f(u16 u) { return __uint_as_float(((unsigned int)u) << 16); }
__device__ inline float fexp2(float x) { return __builtin_amdgcn_exp2f(x); }
__device__ inline float frcp(float x) { return __builtin_amdgcn_rcpf(x); }

union bfrag { bf16x8 b; uint4 q; u16 u[8]; };

// async global->LDS, 16B per lane; lds base wave-uniform, HW scatters lane*16
__device__ inline void gload16(const u16* g, u16* l) {
  __builtin_amdgcn_global_load_lds(
      (const __attribute__((address_space(1))) void*)g,
      (__attribute__((address_space(3))) void*)l, 16, 0, 0);
}

// ---------------- weight transpose-convert: out[n][k] = bf16(in[k][n]) ------
__global__ __launch_bounds__(256)
void transpose_w(const float* __restrict__ in, u16* __restrict__ out,
                 int K, int N, size_t in_lstride, size_t out_lstride,
                 int row_off, int out_ld) {
  __shared__ float tile[32][33];
  int z = blockIdx.z;
  int kk0 = blockIdx.y * 32, nn0 = blockIdx.x * 32;
  int tx = threadIdx.x & 31, ty = threadIdx.x >> 5;
  const float* ip = in + z * in_lstride;
  u16* op = out + z * out_lstride;
#pragma unroll
  for (int i = 0; i < 4; i++)
    tile[ty + i * 8][tx] = ip[(size_t)(kk0 + ty + i * 8) * N + nn0 + tx];
  __syncthreads();
#pragma unroll
  for (int i = 0; i < 4; i++)
    op[(size_t)(row_off + nn0 + ty + i * 8) * out_ld + kk0 + tx] = f2bf(tile[tx][ty + i * 8]);
}

// ---------------- fused lm weights: Wt rows 1536+side*128+hh*16+p -----------
// row[k] = scale * sum_d W[k][hh*64+d] * lw[d][p]
__global__ __launch_bounds__(256)
void wfuse_kernel(const float* __restrict__ Wq, const float* __restrict__ Wk,
                  const float* __restrict__ lmqw, const float* __restrict__ lmkw,
                  u16* __restrict__ Wt) {
  int hh = blockIdx.x, side = blockIdx.y, layer = blockIdx.z;
  const float* W = (side ? Wk : Wq) + (size_t)layer * 512 * 512;
  const float* lw = side ? lmkw : lmqw;
  float scale = side ? 1.0f : BS_QP;
  __shared__ float lws[64][17];
  int t = threadIdx.x;
  for (int i = t; i < 1024; i += 256) lws[i >> 4][i & 15] = lw[i];
  __syncthreads();
  int p = t & 15, kk = t >> 4;
  u16* orow = Wt + (size_t)layer * QKVS * 512 + (size_t)(1536 + side * 128 + hh * 16 + p) * 512;
  for (int kb = 0; kb < 32; kb++) {
    int k = kb * 16 + kk;
    const float* wr = W + (size_t)k * 512 + hh * 64;
    float acc = 0.f;
#pragma unroll
    for (int d = 0; d < 64; d++) acc = fmaf(wr[d], lws[d][p], acc);
    orow[k] = f2bf(acc * scale);
  }
}

// ---------------- zero vtg tail keys 1000..1023 (vtg aliases fp32 t0: -------
// leftover float bytes can decode as bf16 inf/NaN; P=0 x NaN = NaN in PV MFMA)
__global__ __launch_bounds__(192)
void vzero_kernel(u16* __restrict__ vtg) {
  int bh = blockIdx.x;
  int t = threadIdx.x;          // 0..191 = 64 dk rows x 3 uint4
  int dk = t / 3, c = t - dk * 3;
  *(uint4*)(vtg + ((size_t)bh * 64 + dk) * 1024 + 1000 + c * 8) =
      make_uint4(0u, 0u, 0u, 0u);
}

// ---------------- bias assembly: [NL][1792] ---------------------------------
__global__ __launch_bounds__(256)
void concat_bias(const float* __restrict__ bq, const float* __restrict__ bk,
                 const float* __restrict__ bv,
                 const float* __restrict__ lmqw, const float* __restrict__ lmqb,
                 const float* __restrict__ lmkw, const float* __restrict__ lmkb,
                 float* __restrict__ bqkv) {
  int i = blockIdx.x * 256 + threadIdx.x;   // NL*1792
  int l = i / QKVS, j = i % QKVS;
  float v;
  if (j < 512) v = bq[l * 512 + j];
  else if (j < 1024) v = bk[l * 512 + j - 512];
  else if (j < 1536) v = bv[l * 512 + j - 1024];
  else if (j < 1664) {
    int hh = (j - 1536) >> 4, p = (j - 1536) & 15;
    float acc = lmqb[p];
#pragma unroll
    for (int d = 0; d < 64; d++) acc = fmaf(bq[l * 512 + hh * 64 + d], lmqw[d * 16 + p], acc);
    v = acc * BS_QP;
  } else {
    int hh = (j - 1664) >> 4, p = (j - 1664) & 15;
    float acc = lmkb[p];
#pragma unroll
    for (int d = 0; d < 64; d++) acc = fmaf(bk[l * 512 + hh * 64 + d], lmkw[d * 16 + p], acc);
    v = acc;
  }
  bqkv[i] = v;
}

// ---------------- embedding -------------------------------------------------
__global__ __launch_bounds__(512)
void embed_kernel(const float* __restrict__ x, const float* __restrict__ emb_w,
                  const float* __restrict__ emb_b, const float* __restrict__ pe,
                  float* __restrict__ h, u16* __restrict__ h16) {
  int bl = blockIdx.x;
  int l = bl % L_;
  int d = threadIdx.x;
  const float* xr = x + (size_t)bl * F_;
  float acc = emb_b[d] + pe[(size_t)l * DM_ + d];
#pragma unroll
  for (int f = 0; f < F_; f++) acc = fmaf(xr[f], emb_w[f * DM_ + d], acc);
  h[(size_t)bl * DM_ + d] = acc;
  h16[(size_t)bl * DM_ + d] = f2bf(acc);
}

// ---------------- bf16 MFMA GEMM, BK=64; optional v->V^T epilogue routing ---
template<int BN>
__global__ __launch_bounds__(256)
void gemm16(const u16* __restrict__ A, const u16* __restrict__ Bt,
            const float* __restrict__ bias, const float* __restrict__ resid,
            float* __restrict__ C32, u16* __restrict__ C16, u16* __restrict__ vtg,
            int M, int K, int N, int relu, int nscale, float sval) {
  constexpr int NTW = BN / 32;
  constexpr int BG  = BN / 32;
  __shared__ u16 As[128 * 64];
  __shared__ u16 Bs[BN * 64];
  int t = threadIdx.x;
  int w = t >> 6, lane = t & 63;
  int wr = w >> 1, wc = w & 1;
  int mloc = lane & 15, quad = lane >> 4;
  int m0 = blockIdx.y * 128, n0 = blockIdx.x * BN;

  const u16* agp[4]; u16* alds[4];
#pragma unroll
  for (int j = 0; j < 4; j++) {
    int r = w * 32 + j * 8 + (lane >> 3);
    int gm = m0 + r; if (gm > M - 1) gm = M - 1;
    int ch = (lane & 7) ^ (r & 7);
    agp[j] = A + (size_t)gm * K + ch * 8;
    alds[j] = As + (w * 32 + j * 8) * 64;
  }
  const u16* bgp[BG]; u16* blds[BG];
#pragma unroll
  for (int j = 0; j < BG; j++) {
    int r = w * (8 * BG) + j * 8 + (lane >> 3);
    int ch = (lane & 7) ^ (r & 7);
    bgp[j] = Bt + (size_t)(n0 + r) * K + ch * 8;
    blds[j] = Bs + (w * (8 * BG) + j * 8) * 64;
  }
  const u16* apt[2][4];
#pragma unroll
  for (int mi = 0; mi < 4; mi++) {
    int tr = wr * 64 + mi * 16 + mloc;
    apt[0][mi] = As + tr * 64 + ((quad ^ (tr & 7)) * 8);
    apt[1][mi] = As + tr * 64 + (((4 + quad) ^ (tr & 7)) * 8);
  }
  const u16* bpt[2][NTW];
#pragma unroll
  for (int nt = 0; nt < NTW; nt++) {
    int tr = wc * (BN / 2) + nt * 16 + mloc;
    bpt[0][nt] = Bs + tr * 64 + ((quad ^ (tr & 7)) * 8);
    bpt[1][nt] = Bs + tr * 64 + (((4 + quad) ^ (tr & 7)) * 8);
  }

  f32x4 acc[4][NTW];
#pragma unroll
  for (int mi = 0; mi < 4; mi++)
#pragma unroll
    for (int nt = 0; nt < NTW; nt++) acc[mi][nt] = (f32x4){0.f, 0.f, 0.f, 0.f};

  for (int k0 = 0; k0 < K; k0 += 64) {
    __syncthreads();
#pragma unroll
    for (int j = 0; j < 4; j++) gload16(agp[j] + k0, alds[j]);
#pragma unroll
    for (int j = 0; j < BG; j++) gload16(bgp[j] + k0, blds[j]);
    __syncthreads();
#pragma unroll
    for (int kc = 0; kc < 2; kc++) {
      bf16x8 af[4], bv[NTW];
#pragma unroll
      for (int mi = 0; mi < 4; mi++) af[mi] = *(const bf16x8*)apt[kc][mi];
#pragma unroll
      for (int nt = 0; nt < NTW; nt++) bv[nt] = *(const bf16x8*)bpt[kc][nt];
#pragma unroll
      for (int mi = 0; mi < 4; mi++)
#pragma unroll
        for (int nt = 0; nt < NTW; nt++)
          acc[mi][nt] = __builtin_amdgcn_mfma_f32_16x16x32_bf16(af[mi], bv[nt], acc[mi][nt], 0, 0, 0);
    }
  }

#pragma unroll
  for (int mi = 0; mi < 4; mi++) {
    int m_r0 = m0 + wr * 64 + mi * 16 + quad * 4;   // 4-aligned; 1000%4==0
#pragma unroll
    for (int nt = 0; nt < NTW; nt++) {
      int nbase = n0 + wc * (BN / 2) + nt * 16;     // wave-uniform region
      int n = nbase + mloc;
      if (vtg && nbase >= 1024 && nbase < 1536) {
        if (m_r0 < M) {                              // full 4-run valid (M%4==0)
          int bb = (m_r0 * 67109) >> 26;             // m/1000 for m<8000
          int ll = m_r0 - bb * 1000;
          int hh2 = (n - 1024) >> 6, dk = n & 63;
          float bn_ = bias[n];
          union { uint2 d; u16 s[4]; } pk;
#pragma unroll
          for (int r = 0; r < 4; r++) pk.s[r] = f2bf(acc[mi][nt][r] + bn_);
          u16* dst = vtg + ((size_t)(bb * 8 + hh2) * 64 + dk) * 1024 + ll;
          *(uint2*)dst = pk.d;                       // ll%4==0 -> 8B aligned
        }
      } else {
        float bn_ = bias[n];
#pragma unroll
        for (int r = 0; r < 4; r++) {
          int m = m_r0 + r;
          if (m >= M) continue;
          size_t crow = (size_t)m * N;
          float vsum = acc[mi][nt][r] + bn_;
          if (resid) vsum += resid[crow + n];
          if (n < nscale) vsum *= sval;
          if (relu) vsum = fmaxf(vsum, 0.f);
          if (C32) C32[crow + n] = vsum;
          if (C16) C16[crow + n] = f2bf(vsum);
        }
      }
    }
  }
}

// ---------------- MFMA flash attention: chunk-interleaved score->PV ---------
#define KT   128
#define KPLD 24    // Kp row stride (48B)
#define PSLD 40    // per-wave P chunk row stride (16x32 tile)
__global__ __launch_bounds__(256)
void attn_mfma_kernel(const u16* __restrict__ qkv, const u16* __restrict__ vtg,
                      u16* __restrict__ ctx) {
  __shared__ u16 Ks[KT * 64];          // 16384B [key][dk], 8-chunk XOR
  __shared__ u16 Vt[64 * KT];          // 16384B [dk][key], 16-chunk XOR
  __shared__ u16 Kp[KT * KPLD];        // 6144B  [key][p 0..15]
  __shared__ u16 Ps[4 * 16 * PSLD];    // 5120B  per-wave P[16][32]

  // XCD swizzle: all 16 q-tiles of one (b,h) share linear%8 -> same XCD L2
  int Lid = blockIdx.x;                // 0..1023
  int qt = Lid >> 6;
  int bh = ((Lid & 7) << 3) | ((Lid >> 3) & 7);
  int b = bh >> 3, hh = bh & 7;
  int l0 = qt * 64;
  int t = threadIdx.x;
  int wv = t >> 6, lane = t & 63;
  int m = lane & 15, quad = lane >> 4;

  // Q (pre-scaled by 0.125*log2e) + fused qp (pre-scaled by 2*log2e)
  int lq = l0 + wv * 16 + m; if (lq > L_ - 1) lq = L_ - 1;
  const u16* qrow = qkv + (size_t)(b * L_ + lq) * QKVS + hh * DK_;
  bf16x8 qa0 = *(const bf16x8*)(qrow + quad * 8);
  bf16x8 qa1 = *(const bf16x8*)(qrow + 32 + quad * 8);
  bfrag qpa;
  if (quad < 2) {
    qpa.q = *(const uint4*)(qkv + (size_t)(b * L_ + lq) * QKVS + 1536 + hh * P_ + quad * 8);
  } else {
    qpa.q = make_uint4(0u, 0u, 0u, 0u);
  }

  // staging addresses: slot s of row r holds chunk s^(r&7) (r&15 for Vt)
  const u16* ks_g = qkv + ((size_t)b * L_ + (t >> 3)) * QKVS + 512 + hh * DK_
                    + ((t & 7) ^ ((t >> 3) & 7)) * 8;
  u16* ks_l = Ks + (t >> 6) * 512;
  const u16* vt_g = vtg + ((size_t)bh * DK_ + (t >> 4)) * 1024
                    + (((t & 15) ^ (t >> 4)) * 8);
  u16* vt_l = Vt + (t >> 6) * 512;

  f32x4 O[4];
#pragma unroll
  for (int nt = 0; nt < 4; nt++) O[nt] = (f32x4){0.f, 0.f, 0.f, 0.f};
  float lrun[4] = {0.f, 0.f, 0.f, 0.f};

  u16* pw = Ps + wv * (16 * PSLD);
  const u16* pr0 = pw + m * PSLD + quad * 8;
  const f32x4 zz = (f32x4){0.f, 0.f, 0.f, 0.f};

  for (int s0 = 0; s0 < L_; s0 += KT) {
    uint4 p0, p1;
    if (t < KT) {
      int sg2 = s0 + t; if (sg2 > L_ - 1) sg2 = L_ - 1;
      const u16* pr = qkv + (size_t)(b * L_ + sg2) * QKVS + 1664 + hh * P_;
      p0 = *(const uint4*)(pr);
      p1 = *(const uint4*)(pr + 8);
    }
    __syncthreads();   // B1: prev-tile Ks/Vt/Kp reads done
#pragma unroll
    for (int j = 0; j < 4; j++) {
      gload16(ks_g + ((size_t)s0 + j * 32) * QKVS, ks_l + j * 2048);
      gload16(vt_g + s0 + (size_t)j * 16 * 1024, vt_l + j * 2048);
    }
    if (t < KT) {
      *(uint4*)&Kp[t * KPLD]     = p0;
      *(uint4*)&Kp[t * KPLD + 8] = p1;
    }
    __syncthreads();   // B2: tile staged

#pragma unroll
    for (int kc = 0; kc < 4; kc++) {
      float pv2[2][4];
#pragma unroll
      for (int h2 = 0; h2 < 2; h2++) {
        int nt = kc * 2 + h2;
        const u16* kb = Ks + (nt * 16 + m) * 64;
        int x0 = ((quad) ^ (m & 7)) * 8;
        int x1 = ((4 + quad) ^ (m & 7)) * 8;
        f32x4 sacc = __builtin_amdgcn_mfma_f32_16x16x32_bf16(qa0, *(const bf16x8*)(kb + x0), zz, 0, 0, 0);
        sacc = __builtin_amdgcn_mfma_f32_16x16x32_bf16(qa1, *(const bf16x8*)(kb + x1), sacc, 0, 0, 0);
        bf16x8 kpf = *(const bf16x8*)(Kp + (nt * 16 + m) * KPLD + (quad & 1) * 8);
        f32x4 macc = __builtin_amdgcn_mfma_f32_16x16x32_bf16(qpa.b, kpf, zz, 0, 0, 0);
        bool oob = (s0 + nt * 16 + m) >= L_;
#pragma unroll
        for (int r = 0; r < 4; r++) {
          float e = fexp2(macc[r]);                 // macc = 2*log2e*x
          float d = frcp(e + 1.f);
          float th = fmaf(d, -2.f * L2E_, L2E_);    // log2e*tanh(x)
          float s = sacc[r] + th;
          if (oob) s = -3e38f;
          float p = fexp2(s - SHFT_);
          pv2[h2][r] = p;
          lrun[r] += p;
        }
      }
      // P chunk: C-layout -> per-wave 16x32 LDS -> A-layout (same wave)
#pragma unroll
      for (int h2 = 0; h2 < 2; h2++)
#pragma unroll
        for (int r = 0; r < 4; r++)
          pw[(quad * 4 + r) * PSLD + h2 * 16 + m] = f2bf(pv2[h2][r]);
      bf16x8 pa = *(const bf16x8*)pr0;
#pragma unroll
      for (int ntd = 0; ntd < 4; ntd++) {
        const u16* vb = Vt + (ntd * 16 + m) * KT + (((kc * 4 + quad) ^ m) * 8);
        O[ntd] = __builtin_amdgcn_mfma_f32_16x16x32_bf16(pa, *(const bf16x8*)vb, O[ntd], 0, 0, 0);
      }
    }
  }

  float inv[4];
#pragma unroll
  for (int r = 0; r < 4; r++) {
#pragma unroll
    for (int msk = 1; msk < 16; msk <<= 1) lrun[r] += __shfl_xor(lrun[r], msk, 64);
    inv[r] = frcp(lrun[r]);
  }
#pragma unroll
  for (int r = 0; r < 4; r++) {
    int l = l0 + wv * 16 + quad * 4 + r;
    if (l >= L_) continue;
    u16* crow = ctx + ((size_t)(b * L_ + l)) * DM_ + hh * DK_;
#pragma unroll
    for (int nt = 0; nt < 4; nt++) crow[nt * 16 + m] = f2bf(O[nt][r] * inv[r]);
  }
}

// ---------------- layernorm -------------------------------------------------
__global__ __launch_bounds__(256)
void ln_kernel(const float* __restrict__ a, const float* __restrict__ badd,
               const float* __restrict__ g, const float* __restrict__ be,
               float* __restrict__ o, u16* __restrict__ o16) {
  int row = blockIdx.x;
  int t = threadIdx.x;
  size_t base = (size_t)row * DM_;
  float x0 = a[base + t], x1 = a[base + t + 256];
  if (badd) { x0 += badd[base + t]; x1 += badd[base + t + 256]; }
  float s = wave_reduce_sum(x0 + x1);
  float ss = wave_reduce_sum(x0 * x0 + x1 * x1);
  __shared__ float sh_s[4], sh_ss[4];
  int wv = t >> 6, lane = t & 63;
  if (lane == 0) { sh_s[wv] = s; sh_ss[wv] = ss; }
  __syncthreads();
  float S = sh_s[0] + sh_s[1] + sh_s[2] + sh_s[3];
  float SS = sh_ss[0] + sh_ss[1] + sh_ss[2] + sh_ss[3];
  float mean = S * (1.0f / DM_);
  float var = SS * (1.0f / DM_) - mean * mean;
  float rstd = rsqrtf(var + EPS_);
  float r0 = (x0 - mean) * rstd * g[t] + be[t];
  float r1 = (x1 - mean) * rstd * g[t + 256] + be[t + 256];
  o[base + t] = r0; o[base + t + 256] = r1;
  if (o16) { o16[base + t] = f2bf(r0); o16[base + t + 256] = f2bf(r1); }
}

// ---------------- fused double layernorm ------------------------------------
__global__ __launch_bounds__(256)
void ln2x_kernel(const float* __restrict__ hin, const float* __restrict__ y,
                 const float* __restrict__ g, const float* __restrict__ be,
                 float* __restrict__ o32, u16* __restrict__ o16) {
  int row = blockIdx.x;
  int t = threadIdx.x;
  size_t base = (size_t)row * DM_;
  float y0 = y[base + t], y1 = y[base + t + 256];
  float x0 = hin[base + t] + y0, x1 = hin[base + t + 256] + y1;
  __shared__ float sh_s[4], sh_ss[4];
  int wv = t >> 6, lane = t & 63;
  float g0 = g[t], g1v = g[t + 256], b0 = be[t], b1v = be[t + 256];

  float s = wave_reduce_sum(x0 + x1);
  float ss = wave_reduce_sum(x0 * x0 + x1 * x1);
  if (lane == 0) { sh_s[wv] = s; sh_ss[wv] = ss; }
  __syncthreads();
  float S = sh_s[0] + sh_s[1] + sh_s[2] + sh_s[3];
  float SS = sh_ss[0] + sh_ss[1] + sh_ss[2] + sh_ss[3];
  float mean = S * (1.0f / DM_);
  float var = SS * (1.0f / DM_) - mean * mean;
  float rstd = rsqrtf(var + EPS_);
  float h20 = (x0 - mean) * rstd * g0 + b0 + y0;
  float h21 = (x1 - mean) * rstd * g1v + b1v + y1;
  __syncthreads();

  s = wave_reduce_sum(h20 + h21);
  ss = wave_reduce_sum(h20 * h20 + h21 * h21);
  if (lane == 0) { sh_s[wv] = s; sh_ss[wv] = ss; }
  __syncthreads();
  S = sh_s[0] + sh_s[1] + sh_s[2] + sh_s[3];
  SS = sh_ss[0] + sh_ss[1] + sh_ss[2] + sh_ss[3];
  mean = S * (1.0f / DM_);
  var = SS * (1.0f / DM_) - mean * mean;
  rstd = rsqrtf(var + EPS_);
  float r0 = (h20 - mean) * rstd * g0 + b0;
  float r1 = (h21 - mean) * rstd * g1v + b1v;
  o32[base + t] = r0; o32[base + t + 256] = r1;
  if (o16) { o16[base + t] = f2bf(r0); o16[base + t + 256] = f2bf(r1); }
}

// ---------------- final head ------------------------------------------------
__global__ __launch_bounds__(512)
void final_kernel(const float* __restrict__ h, const float* __restrict__ gn,
                  const float* __restrict__ bn, const float* __restrict__ fcw,
                  const float* __restrict__ fcb, float* __restrict__ out) {
  int b = blockIdx.x;
  int t = threadIdx.x;
  size_t base = ((size_t)b * L_ + (L_ - 1)) * DM_;
  float x = h[base + t];
  float s = wave_reduce_sum(x);
  float ss = wave_reduce_sum(x * x);
  __shared__ float sh_s[8], sh_ss[8];
  int wv = t >> 6, lane = t & 63;
  if (lane == 0) { sh_s[wv] = s; sh_ss[wv] = ss; }
  __syncthreads();
  float S = 0.f, SS = 0.f;
#pragma unroll
  for (int i = 0; i < 8; i++) { S += sh_s[i]; SS += sh_ss[i]; }
  float mean = S * (1.0f / DM_);
  float var = SS * (1.0f / DM_) - mean * mean;
  float rstd = rsqrtf(var + EPS_);
  __shared__ float hn[DM_];
  hn[t] = (x - mean) * rstd * gn[t] + bn[t];
  __syncthreads();
  if (t < PRED_) {
    float acc = fcb[t];
#pragma unroll 8
    for (int d = 0; d < DM_; d++) acc = fmaf(hn[d], fcw[d * PRED_ + t], acc);
    out[b * PRED_ + t] = acc;
  }
}

// ---------------- driver ----------------
extern "C" void kernel_launch(void* const* d_in, const int* in_sizes, int n_in,
                              void* d_out, int out_size, void* d_ws, size_t ws_size,
                              hipStream_t stream) {
  const float* x     = (const float*)d_in[0];
  const float* emb_w = (const float*)d_in[1];
  const float* emb_b = (const float*)d_in[2];
  const float* pe    = (const float*)d_in[3];
  const float* Wq = (const float*)d_in[4];  const float* bq = (const float*)d_in[5];
  const float* Wk = (const float*)d_in[6];  const float* bk = (const float*)d_in[7];
  const float* Wv = (const float*)d_in[8];  const float* bv = (const float*)d_in[9];
  const float* Wo = (const float*)d_in[10]; const float* bo = (const float*)d_in[11];
  const float* W1 = (const float*)d_in[12]; const float* b1 = (const float*)d_in[13];
  const float* W2 = (const float*)d_in[14]; const float* b2 = (const float*)d_in[15];
  const float* g1 = (const float*)d_in[16]; const float* be1 = (const float*)d_in[17];
  const float* g2 = (const float*)d_in[18]; const float* be2 = (const float*)d_in[19];
  const float* lm_qw = (const float*)d_in[20]; const float* lm_qb = (const float*)d_in[21];
  const float* lm_kw = (const float*)d_in[22]; const float* lm_kb = (const float*)d_in[23];
  const float* gn = (const float*)d_in[24]; const float* bn = (const float*)d_in[25];
  const float* fc_w = (const float*)d_in[26]; const float* fc_b = (const float*)d_in[27];
  float* out = (float*)d_out;

  const size_t ROWS = (size_t)B_ * L_;     // 8000
  u16* qkv16 = (u16*)d_ws;                               // [8000][1792] (v gap unused)
  u16* ctx16 = qkv16 + ROWS * QKVS;                      // [8000][512]
  u16* ffn1  = qkv16;                                    // [8000][2048] alias (fits in qkv+ctx)
  u16* h16   = ctx16 + ROWS * DM_;                       // [8000][512]
  u16* Wqkv_t = h16 + ROWS * DM_;                        // [NL][1792][512]
  u16* Wo_t   = Wqkv_t + (size_t)NL_ * QKVS * DM_;       // [NL][512][512]
  u16* W1_t   = Wo_t + (size_t)NL_ * DM_ * DM_;          // [NL][2048][512]
  u16* W2_t   = W1_t + (size_t)NL_ * DFF_ * DM_;         // [NL][512][2048]
  float* h32  = (float*)(W2_t + (size_t)NL_ * DM_ * DFF_);
  float* t0   = h32 + ROWS * DM_;
  float* bqkv = t0 + ROWS * DM_;                         // [NL][1792]
  u16* vtg    = (u16*)t0;   // [64][64][1024] = 8.4 MB, aliases t0 (dead until wo-GEMM)

  transpose_w<<<dim3(16, 16, NL_), 256, 0, stream>>>(Wq, Wqkv_t, DM_, DM_, (size_t)DM_ * DM_, (size_t)QKVS * DM_, 0, DM_);
  transpose_w<<<dim3(16, 16, NL_), 256, 0, stream>>>(Wk, Wqkv_t, DM_, DM_, (size_t)DM_ * DM_, (size_t)QKVS * DM_, 512, DM_);
  transpose_w<<<dim3(16, 16, NL_), 256, 0, stream>>>(Wv, Wqkv_t, DM_, DM_, (size_t)DM_ * DM_, (size_t)QKVS * DM_, 1024, DM_);
  transpose_w<<<dim3(16, 16, NL_), 256, 0, stream>>>(Wo, Wo_t, DM_, DM_, (size_t)DM_ * DM_, (size_t)DM_ * DM_, 0, DM_);
  transpose_w<<<dim3(64, 16, NL_), 256, 0, stream>>>(W1, W1_t, DM_, DFF_, (size_t)DM_ * DFF_, (size_t)DFF_ * DM_, 0, DM_);
  transpose_w<<<dim3(16, 64, NL_), 256, 0, stream>>>(W2, W2_t, DFF_, DM_, (size_t)DFF_ * DM_, (size_t)DM_ * DFF_, 0, DFF_);
  wfuse_kernel<<<dim3(H_, 2, NL_), 256, 0, stream>>>(Wq, Wk, lm_qw, lm_kw, Wqkv_t);
  concat_bias<<<NL_ * QKVS / 256, 256, 0, stream>>>(bq, bk, bv, lm_qw, lm_qb, lm_kw, lm_kb, bqkv);

  embed_kernel<<<dim3((unsigned)ROWS), 512, 0, stream>>>(x, emb_w, emb_b, pe, h32, h16);

  dim3 g_qkv(QKVS / 128, 63);    // (14, 63)
  dim3 g_ffn1(DFF_ / 128, 63);
  dim3 g_n512(DM_ / 64, 63);
  dim3 g_attn(1024);

  for (int i = 0; i < NL_; i++) {
    gemm16<128><<<g_qkv, 256, 0, stream>>>(h16, Wqkv_t + (size_t)i * QKVS * DM_,
        bqkv + i * QKVS, nullptr, nullptr, qkv16, vtg, 8000, DM_, QKVS, 0, 512, C_QS);

    vzero_kernel<<<64, 192, 0, stream>>>(vtg);

    attn_mfma_kernel<<<g_attn, 256, 0, stream>>>(qkv16, vtg, ctx16);

    gemm16<64><<<g_n512, 256, 0, stream>>>(ctx16, Wo_t + (size_t)i * DM_ * DM_,
        bo + i * DM_, h32, t0, nullptr, nullptr, 8000, DM_, DM_, 0, 0, 1.0f);
    ln_kernel<<<dim3((unsigned)ROWS), 256, 0, stream>>>(t0, nullptr, g1 + i * DM_, be1 + i * DM_, h32, h16);

    gemm16<128><<<g_ffn1, 256, 0, stream>>>(h16, W1_t + (size_t)i * DFF_ * DM_,
        b1 + i * DFF_, nullptr, nullptr, ffn1, nullptr, 8000, DM_, DFF_, 1, 0, 1.0f);
    gemm16<64><<<g_n512, 256, 0, stream>>>(ffn1, W2_t + (size_t)i * DM_ * DFF_,
        b2 + i * DM_, nullptr, t0, nullptr, nullptr, 8000, DFF_, DM_, 0, 0, 1.0f);

    ln2x_kernel<<<dim3((unsigned)ROWS), 256, 0, stream>>>(h32, t0, g2 + i * DM_, be2 + i * DM_, h32, h16);
  }

  final_kernel<<<B_, 512, 0, stream>>>(h32, gn, bn, fc_w, fc_b, out);
}

// Round 10
// 1107.051 us; speedup vs baseline: 1.4625x; 1.1049x over previous
//
#include <hip/hip_runtime.h>
#include <math.h>

// Problem constants (PCUTransformer)
#define B_    8
#define L_    1000
#define F_    7
#define DM_   512
#define H_    8
#define DFF_  2048
#define NL_   4
#define PRED_ 50
#define DK_   64
#define P_    16
#define EPS_  1e-5f
#define QKVS  1792      // fused row: q(512) k(512) v-gap(512) qp(128) kp(128)

#define L2E_   1.4426950408889634f
#define C_QS   0.18033688011112042f   // 0.125 * log2(e) folded into q
#define BS_QP  2.8853900817779268f    // 2*log2(e) folded into fused qp weights
#define SHFT_  24.0f                  // fixed softmax shift (cancels in normalize)

typedef unsigned short u16;
typedef __bf16 bf16x8 __attribute__((ext_vector_type(8)));
typedef float  f32x4  __attribute__((ext_vector_type(4)));

// ---------------- helpers ----------------
__device__ inline float wave_reduce_sum(float x) {
#pragma unroll
  for (int off = 32; off >= 1; off >>= 1) x += __shfl_xor(x, off, 64);
  return x;
}
__device__ inline u16 f2bf(float f) {   // RNE float->bf16 bits
  unsigned int u = __float_as_uint(f);
  unsigned int r = u + 0x7FFFu + ((u >> 16) & 1u);
  return (u16)(r >> 16);
}
__device__ inline unsigned int pack2(float a, float b) {
  return (unsigned int)f2bf(a) | ((unsigned int)f2bf(b) << 16);
}
__device__ inline float bf2f(u16 u) { return __uint_as_float(((unsigned int)u) << 16); }
__device__ inline float fexp2(float x) { return __builtin_amdgcn_exp2f(x); }
__device__ inline float frcp(float x) { return __builtin_amdgcn_rcpf(x); }

union bfrag { bf16x8 b; uint4 q; u16 u[8]; };

// async global->LDS, 16B per lane; lds base wave-uniform, HW scatters lane*16
__device__ inline void gload16(const u16* g, u16* l) {
  __builtin_amdgcn_global_load_lds(
      (const __attribute__((address_space(1))) void*)g,
      (__attribute__((address_space(3))) void*)l, 16, 0, 0);
}

// ---------------- weight transpose-convert: out[n][k] = bf16(in[k][n]) ------
__global__ __launch_bounds__(256)
void transpose_w(const float* __restrict__ in, u16* __restrict__ out,
                 int K, int N, size_t in_lstride, size_t out_lstride,
                 int row_off, int out_ld) {
  __shared__ float tile[32][33];
  int z = blockIdx.z;
  int kk0 = blockIdx.y * 32, nn0 = blockIdx.x * 32;
  int tx = threadIdx.x & 31, ty = threadIdx.x >> 5;
  const float* ip = in + z * in_lstride;
  u16* op = out + z * out_lstride;
#pragma unroll
  for (int i = 0; i < 4; i++)
    tile[ty + i * 8][tx] = ip[(size_t)(kk0 + ty + i * 8) * N + nn0 + tx];
  __syncthreads();
#pragma unroll
  for (int i = 0; i < 4; i++)
    op[(size_t)(row_off + nn0 + ty + i * 8) * out_ld + kk0 + tx] = f2bf(tile[tx][ty + i * 8]);
}

// ---------------- fused lm weights: Wt rows 1536+side*128+hh*16+p -----------
__global__ __launch_bounds__(256)
void wfuse_kernel(const float* __restrict__ Wq, const float* __restrict__ Wk,
                  const float* __restrict__ lmqw, const float* __restrict__ lmkw,
                  u16* __restrict__ Wt) {
  int hh = blockIdx.x, side = blockIdx.y, layer = blockIdx.z;
  const float* W = (side ? Wk : Wq) + (size_t)layer * 512 * 512;
  const float* lw = side ? lmkw : lmqw;
  float scale = side ? 1.0f : BS_QP;
  __shared__ float lws[64][17];
  int t = threadIdx.x;
  for (int i = t; i < 1024; i += 256) lws[i >> 4][i & 15] = lw[i];
  __syncthreads();
  int p = t & 15, kk = t >> 4;
  u16* orow = Wt + (size_t)layer * QKVS * 512 + (size_t)(1536 + side * 128 + hh * 16 + p) * 512;
  for (int kb = 0; kb < 32; kb++) {
    int k = kb * 16 + kk;
    const float* wr = W + (size_t)k * 512 + hh * 64;
    float acc = 0.f;
#pragma unroll
    for (int d = 0; d < 64; d++) acc = fmaf(wr[d], lws[d][p], acc);
    orow[k] = f2bf(acc * scale);
  }
}

// ---------------- bias assembly: [NL][1792] ---------------------------------
__global__ __launch_bounds__(256)
void concat_bias(const float* __restrict__ bq, const float* __restrict__ bk,
                 const float* __restrict__ bv,
                 const float* __restrict__ lmqw, const float* __restrict__ lmqb,
                 const float* __restrict__ lmkw, const float* __restrict__ lmkb,
                 float* __restrict__ bqkv) {
  int i = blockIdx.x * 256 + threadIdx.x;   // NL*1792
  int l = i / QKVS, j = i % QKVS;
  float v;
  if (j < 512) v = bq[l * 512 + j];
  else if (j < 1024) v = bk[l * 512 + j - 512];
  else if (j < 1536) v = bv[l * 512 + j - 1024];
  else if (j < 1664) {
    int hh = (j - 1536) >> 4, p = (j - 1536) & 15;
    float acc = lmqb[p];
#pragma unroll
    for (int d = 0; d < 64; d++) acc = fmaf(bq[l * 512 + hh * 64 + d], lmqw[d * 16 + p], acc);
    v = acc * BS_QP;
  } else {
    int hh = (j - 1664) >> 4, p = (j - 1664) & 15;
    float acc = lmkb[p];
#pragma unroll
    for (int d = 0; d < 64; d++) acc = fmaf(bk[l * 512 + hh * 64 + d], lmkw[d * 16 + p], acc);
    v = acc;
  }
  bqkv[i] = v;
}

// ---------------- embedding (bf16 out) --------------------------------------
__global__ __launch_bounds__(512)
void embed_kernel(const float* __restrict__ x, const float* __restrict__ emb_w,
                  const float* __restrict__ emb_b, const float* __restrict__ pe,
                  u16* __restrict__ h16) {
  int bl = blockIdx.x;
  int l = bl % L_;
  int d = threadIdx.x;
  const float* xr = x + (size_t)bl * F_;
  float acc = emb_b[d] + pe[(size_t)l * DM_ + d];
#pragma unroll
  for (int f = 0; f < F_; f++) acc = fmaf(xr[f], emb_w[f * DM_ + d], acc);
  h16[(size_t)bl * DM_ + d] = f2bf(acc);
}

// ---------------- bf16 MFMA GEMM, BK=64; optional v->V^T epilogue routing ---
template<int BN>
__global__ __launch_bounds__(256)
void gemm16(const u16* __restrict__ A, const u16* __restrict__ Bt,
            const float* __restrict__ bias, const u16* __restrict__ resid,
            u16* __restrict__ C16, u16* __restrict__ vtg,
            int M, int K, int N, int relu, int nscale, float sval) {
  constexpr int NTW = BN / 32;
  constexpr int BG  = BN / 32;
  __shared__ u16 As[128 * 64];
  __shared__ u16 Bs[BN * 64];
  int t = threadIdx.x;
  int w = t >> 6, lane = t & 63;
  int wr = w >> 1, wc = w & 1;
  int mloc = lane & 15, quad = lane >> 4;
  int m0 = blockIdx.y * 128, n0 = blockIdx.x * BN;

  const u16* agp[4]; u16* alds[4];
#pragma unroll
  for (int j = 0; j < 4; j++) {
    int r = w * 32 + j * 8 + (lane >> 3);
    int gm = m0 + r; if (gm > M - 1) gm = M - 1;
    int ch = (lane & 7) ^ (r & 7);
    agp[j] = A + (size_t)gm * K + ch * 8;
    alds[j] = As + (w * 32 + j * 8) * 64;
  }
  const u16* bgp[BG]; u16* blds[BG];
#pragma unroll
  for (int j = 0; j < BG; j++) {
    int r = w * (8 * BG) + j * 8 + (lane >> 3);
    int ch = (lane & 7) ^ (r & 7);
    bgp[j] = Bt + (size_t)(n0 + r) * K + ch * 8;
    blds[j] = Bs + (w * (8 * BG) + j * 8) * 64;
  }
  const u16* apt[2][4];
#pragma unroll
  for (int mi = 0; mi < 4; mi++) {
    int tr = wr * 64 + mi * 16 + mloc;
    apt[0][mi] = As + tr * 64 + ((quad ^ (tr & 7)) * 8);
    apt[1][mi] = As + tr * 64 + (((4 + quad) ^ (tr & 7)) * 8);
  }
  const u16* bpt[2][NTW];
#pragma unroll
  for (int nt = 0; nt < NTW; nt++) {
    int tr = wc * (BN / 2) + nt * 16 + mloc;
    bpt[0][nt] = Bs + tr * 64 + ((quad ^ (tr & 7)) * 8);
    bpt[1][nt] = Bs + tr * 64 + (((4 + quad) ^ (tr & 7)) * 8);
  }

  f32x4 acc[4][NTW];
#pragma unroll
  for (int mi = 0; mi < 4; mi++)
#pragma unroll
    for (int nt = 0; nt < NTW; nt++) acc[mi][nt] = (f32x4){0.f, 0.f, 0.f, 0.f};

  for (int k0 = 0; k0 < K; k0 += 64) {
    __syncthreads();
#pragma unroll
    for (int j = 0; j < 4; j++) gload16(agp[j] + k0, alds[j]);
#pragma unroll
    for (int j = 0; j < BG; j++) gload16(bgp[j] + k0, blds[j]);
    __syncthreads();
#pragma unroll
    for (int kc = 0; kc < 2; kc++) {
      bf16x8 af[4], bv[NTW];
#pragma unroll
      for (int mi = 0; mi < 4; mi++) af[mi] = *(const bf16x8*)apt[kc][mi];
#pragma unroll
      for (int nt = 0; nt < NTW; nt++) bv[nt] = *(const bf16x8*)bpt[kc][nt];
#pragma unroll
      for (int mi = 0; mi < 4; mi++)
#pragma unroll
        for (int nt = 0; nt < NTW; nt++)
          acc[mi][nt] = __builtin_amdgcn_mfma_f32_16x16x32_bf16(af[mi], bv[nt], acc[mi][nt], 0, 0, 0);
    }
  }

#pragma unroll
  for (int mi = 0; mi < 4; mi++) {
    int m_r0 = m0 + wr * 64 + mi * 16 + quad * 4;   // 4-aligned; 1000%4==0
#pragma unroll
    for (int nt = 0; nt < NTW; nt++) {
      int nbase = n0 + wc * (BN / 2) + nt * 16;     // wave-uniform region
      int n = nbase + mloc;
      if (vtg && nbase >= 1024 && nbase < 1536) {
        if (m_r0 < M) {                              // full 4-run valid (M%4==0)
          int bb = (m_r0 * 67109) >> 26;             // m/1000 for m<8000
          int ll = m_r0 - bb * 1000;
          int hh2 = (n - 1024) >> 6, dk = n & 63;
          float bn_ = bias[n];
          union { uint2 d; u16 s[4]; } pk;
#pragma unroll
          for (int r = 0; r < 4; r++) pk.s[r] = f2bf(acc[mi][nt][r] + bn_);
          u16* dst = vtg + ((size_t)(bb * 8 + hh2) * 64 + dk) * 1024 + ll;
          *(uint2*)dst = pk.d;                       // ll%4==0 -> 8B aligned
        }
      } else {
        float bn_ = bias[n];
#pragma unroll
        for (int r = 0; r < 4; r++) {
          int m = m_r0 + r;
          if (m >= M) continue;
          size_t crow = (size_t)m * N;
          float vsum = acc[mi][nt][r] + bn_;
          if (resid) vsum += bf2f(resid[crow + n]);
          if (n < nscale) vsum *= sval;
          if (relu) vsum = fmaxf(vsum, 0.f);
          C16[crow + n] = f2bf(vsum);
        }
      }
    }
  }
}

// ---------------- MFMA flash attention: 64-key tiles, chunk-interleaved -----
// LDS 24KB -> 6 blocks/CU (grid 1024 = 4/CU fully resident, no tail wave).
#define KT   64
#define KPLD 24    // Kp row stride (48B)
#define PSLD 40    // per-wave P chunk row stride (16x32 tile)
__global__ __launch_bounds__(256)
void attn_mfma_kernel(const u16* __restrict__ qkv, const u16* __restrict__ vtg,
                      u16* __restrict__ ctx) {
  __shared__ u16 Ks[KT * 64];          // 8192B [key][dk], 8-chunk XOR
  __shared__ u16 Vt[64 * KT];          // 8192B [dk][key], 8-chunk XOR
  __shared__ u16 Kp[KT * KPLD];        // 3072B [key][p 0..15]
  __shared__ u16 Ps[4 * 16 * PSLD];    // 5120B per-wave P[16][32]

  // XCD swizzle: all 16 q-tiles of one (b,h) share linear%8 -> same XCD L2
  int Lid = blockIdx.x;                // 0..1023
  int qt = Lid >> 6;
  int bh = ((Lid & 7) << 3) | ((Lid >> 3) & 7);
  int b = bh >> 3, hh = bh & 7;
  int l0 = qt * 64;
  int t = threadIdx.x;
  int wv = t >> 6, lane = t & 63;
  int m = lane & 15, quad = lane >> 4;

  // Q (pre-scaled by 0.125*log2e) + fused qp (pre-scaled by 2*log2e)
  int lq = l0 + wv * 16 + m; if (lq > L_ - 1) lq = L_ - 1;
  const u16* qrow = qkv + (size_t)(b * L_ + lq) * QKVS + hh * DK_;
  bf16x8 qa0 = *(const bf16x8*)(qrow + quad * 8);
  bf16x8 qa1 = *(const bf16x8*)(qrow + 32 + quad * 8);
  bfrag qpa;
  if (quad < 2) {
    qpa.q = *(const uint4*)(qkv + (size_t)(b * L_ + lq) * QKVS + 1536 + hh * P_ + quad * 8);
  } else {
    qpa.q = make_uint4(0u, 0u, 0u, 0u);
  }

  // staging: slot s of row r holds chunk s^(r&7); 8 rows/wave/round, 2 rounds
  const u16* ks_g = qkv + ((size_t)b * L_ + (t >> 3)) * QKVS + 512 + hh * DK_
                    + ((t & 7) ^ ((t >> 3) & 7)) * 8;
  u16* ks_l = Ks + (t >> 6) * 512;
  const u16* vt_g = vtg + ((size_t)bh * DK_ + (t >> 3)) * 1024
                    + ((t & 7) ^ ((t >> 3) & 7)) * 8;
  u16* vt_l = Vt + (t >> 6) * 512;

  f32x4 O[4];
#pragma unroll
  for (int nt = 0; nt < 4; nt++) O[nt] = (f32x4){0.f, 0.f, 0.f, 0.f};
  float lrun[4] = {0.f, 0.f, 0.f, 0.f};

  u16* pw = Ps + wv * (16 * PSLD);
  const u16* pr0 = pw + m * PSLD + quad * 8;
  const f32x4 zz = (f32x4){0.f, 0.f, 0.f, 0.f};

  for (int s0 = 0; s0 < L_; s0 += KT) {
    uint4 p0, p1;
    if (t < KT) {
      int sg2 = s0 + t; if (sg2 > L_ - 1) sg2 = L_ - 1;
      const u16* pr = qkv + (size_t)(b * L_ + sg2) * QKVS + 1664 + hh * P_;
      p0 = *(const uint4*)(pr);
      p1 = *(const uint4*)(pr + 8);
    }
    __syncthreads();   // B1: prev-tile Ks/Vt/Kp reads done
#pragma unroll
    for (int j = 0; j < 2; j++) {
      gload16(ks_g + ((size_t)s0 + j * 32) * QKVS, ks_l + j * 2048);
      gload16(vt_g + s0 + (size_t)j * 32 * 1024, vt_l + j * 2048);
    }
    if (t < KT) {
      *(uint4*)&Kp[t * KPLD]     = p0;
      *(uint4*)&Kp[t * KPLD + 8] = p1;
    }
    __syncthreads();   // B2: tile staged

#pragma unroll
    for (int kc = 0; kc < 2; kc++) {
      float pv2[2][4];
#pragma unroll
      for (int h2 = 0; h2 < 2; h2++) {
        int nt = kc * 2 + h2;
        const u16* kb = Ks + (nt * 16 + m) * 64;
        int x0 = ((quad) ^ (m & 7)) * 8;
        int x1 = ((4 + quad) ^ (m & 7)) * 8;
        f32x4 sacc = __builtin_amdgcn_mfma_f32_16x16x32_bf16(qa0, *(const bf16x8*)(kb + x0), zz, 0, 0, 0);
        sacc = __builtin_amdgcn_mfma_f32_16x16x32_bf16(qa1, *(const bf16x8*)(kb + x1), sacc, 0, 0, 0);
        bf16x8 kpf = *(const bf16x8*)(Kp + (nt * 16 + m) * KPLD + (quad & 1) * 8);
        f32x4 macc = __builtin_amdgcn_mfma_f32_16x16x32_bf16(qpa.b, kpf, zz, 0, 0, 0);
        bool oob = (s0 + nt * 16 + m) >= L_;
#pragma unroll
        for (int r = 0; r < 4; r++) {
          float e = fexp2(macc[r]);                 // macc = 2*log2e*x
          float d = frcp(e + 1.f);
          float th = fmaf(d, -2.f * L2E_, L2E_);    // log2e*tanh(x)
          float s = sacc[r] + th;
          if (oob) s = -3e38f;
          float p = fexp2(s - SHFT_);
          pv2[h2][r] = p;
          lrun[r] += p;
        }
      }
      // P chunk: C-layout -> per-wave 16x32 LDS -> A-layout (same wave)
#pragma unroll
      for (int h2 = 0; h2 < 2; h2++)
#pragma unroll
        for (int r = 0; r < 4; r++)
          pw[(quad * 4 + r) * PSLD + h2 * 16 + m] = f2bf(pv2[h2][r]);
      bf16x8 pa = *(const bf16x8*)pr0;
#pragma unroll
      for (int ntd = 0; ntd < 4; ntd++) {
        const u16* vb = Vt + (ntd * 16 + m) * KT + (((kc * 4 + quad) ^ (m & 7)) * 8);
        O[ntd] = __builtin_amdgcn_mfma_f32_16x16x32_bf16(pa, *(const bf16x8*)vb, O[ntd], 0, 0, 0);
      }
    }
  }

  float inv[4];
#pragma unroll
  for (int r = 0; r < 4; r++) {
#pragma unroll
    for (int msk = 1; msk < 16; msk <<= 1) lrun[r] += __shfl_xor(lrun[r], msk, 64);
    inv[r] = frcp(lrun[r]);
  }
#pragma unroll
  for (int r = 0; r < 4; r++) {
    int l = l0 + wv * 16 + quad * 4 + r;
    if (l >= L_) continue;
    u16* crow = ctx + ((size_t)(b * L_ + l)) * DM_ + hh * DK_;
#pragma unroll
    for (int nt = 0; nt < 4; nt++) crow[nt * 16 + m] = f2bf(O[nt][r] * inv[r]);
  }
}

// ---------------- layernorm (bf16 in/out): o = LN(a) * g + be ---------------
__global__ __launch_bounds__(256)
void ln_kernel(const u16* __restrict__ a, const float* __restrict__ g,
               const float* __restrict__ be, u16* __restrict__ o) {
  int row = blockIdx.x;
  int t = threadIdx.x;
  size_t base = (size_t)row * DM_;
  unsigned int av = *(const unsigned int*)(a + base + 2 * t);
  float x0 = bf2f((u16)av), x1 = bf2f((u16)(av >> 16));
  float s = wave_reduce_sum(x0 + x1);
  float ss = wave_reduce_sum(x0 * x0 + x1 * x1);
  __shared__ float sh_s[4], sh_ss[4];
  int wv = t >> 6, lane = t & 63;
  if (lane == 0) { sh_s[wv] = s; sh_ss[wv] = ss; }
  __syncthreads();
  float S = sh_s[0] + sh_s[1] + sh_s[2] + sh_s[3];
  float SS = sh_ss[0] + sh_ss[1] + sh_ss[2] + sh_ss[3];
  float mean = S * (1.0f / DM_);
  float var = SS * (1.0f / DM_) - mean * mean;
  float rstd = rsqrtf(var + EPS_);
  float r0 = (x0 - mean) * rstd * g[2 * t] + be[2 * t];
  float r1 = (x1 - mean) * rstd * g[2 * t + 1] + be[2 * t + 1];
  *(unsigned int*)(o + base + 2 * t) = pack2(r0, r1);
}

// ---------------- fused double layernorm (bf16): h = LN(LN(h+y)+y) ----------
__global__ __launch_bounds__(256)
void ln2x_kernel(const u16* __restrict__ hin, const u16* __restrict__ y,
                 const float* __restrict__ g, const float* __restrict__ be,
                 u16* __restrict__ o16) {
  int row = blockIdx.x;
  int t = threadIdx.x;
  size_t base = (size_t)row * DM_;
  unsigned int hv = *(const unsigned int*)(hin + base + 2 * t);
  unsigned int yv = *(const unsigned int*)(y + base + 2 * t);
  float y0 = bf2f((u16)yv), y1 = bf2f((u16)(yv >> 16));
  float x0 = bf2f((u16)hv) + y0, x1 = bf2f((u16)(hv >> 16)) + y1;
  __shared__ float sh_s[4], sh_ss[4];
  int wv = t >> 6, lane = t & 63;
  float g0 = g[2 * t], g1v = g[2 * t + 1], b0 = be[2 * t], b1v = be[2 * t + 1];

  float s = wave_reduce_sum(x0 + x1);
  float ss = wave_reduce_sum(x0 * x0 + x1 * x1);
  if (lane == 0) { sh_s[wv] = s; sh_ss[wv] = ss; }
  __syncthreads();
  float S = sh_s[0] + sh_s[1] + sh_s[2] + sh_s[3];
  float SS = sh_ss[0] + sh_ss[1] + sh_ss[2] + sh_ss[3];
  float mean = S * (1.0f / DM_);
  float var = SS * (1.0f / DM_) - mean * mean;
  float rstd = rsqrtf(var + EPS_);
  float h20 = (x0 - mean) * rstd * g0 + b0 + y0;
  float h21 = (x1 - mean) * rstd * g1v + b1v + y1;
  __syncthreads();

  s = wave_reduce_sum(h20 + h21);
  ss = wave_reduce_sum(h20 * h20 + h21 * h21);
  if (lane == 0) { sh_s[wv] = s; sh_ss[wv] = ss; }
  __syncthreads();
  S = sh_s[0] + sh_s[1] + sh_s[2] + sh_s[3];
  SS = sh_ss[0] + sh_ss[1] + sh_ss[2] + sh_ss[3];
  mean = S * (1.0f / DM_);
  var = SS * (1.0f / DM_) - mean * mean;
  rstd = rsqrtf(var + EPS_);
  float r0 = (h20 - mean) * rstd * g0 + b0;
  float r1 = (h21 - mean) * rstd * g1v + b1v;
  *(unsigned int*)(o16 + base + 2 * t) = pack2(r0, r1);
}

// ---------------- final head (bf16 in) --------------------------------------
__global__ __launch_bounds__(512)
void final_kernel(const u16* __restrict__ h, const float* __restrict__ gn,
                  const float* __restrict__ bn, const float* __restrict__ fcw,
                  const float* __restrict__ fcb, float* __restrict__ out) {
  int b = blockIdx.x;
  int t = threadIdx.x;
  size_t base = ((size_t)b * L_ + (L_ - 1)) * DM_;
  float x = bf2f(h[base + t]);
  float s = wave_reduce_sum(x);
  float ss = wave_reduce_sum(x * x);
  __shared__ float sh_s[8], sh_ss[8];
  int wv = t >> 6, lane = t & 63;
  if (lane == 0) { sh_s[wv] = s; sh_ss[wv] = ss; }
  __syncthreads();
  float S = 0.f, SS = 0.f;
#pragma unroll
  for (int i = 0; i < 8; i++) { S += sh_s[i]; SS += sh_ss[i]; }
  float mean = S * (1.0f / DM_);
  float var = SS * (1.0f / DM_) - mean * mean;
  float rstd = rsqrtf(var + EPS_);
  __shared__ float hn[DM_];
  hn[t] = (x - mean) * rstd * gn[t] + bn[t];
  __syncthreads();
  if (t < PRED_) {
    float acc = fcb[t];
#pragma unroll 8
    for (int d = 0; d < DM_; d++) acc = fmaf(hn[d], fcw[d * PRED_ + t], acc);
    out[b * PRED_ + t] = acc;
  }
}

// ---------------- driver ----------------
extern "C" void kernel_launch(void* const* d_in, const int* in_sizes, int n_in,
                              void* d_out, int out_size, void* d_ws, size_t ws_size,
                              hipStream_t stream) {
  const float* x     = (const float*)d_in[0];
  const float* emb_w = (const float*)d_in[1];
  const float* emb_b = (const float*)d_in[2];
  const float* pe    = (const float*)d_in[3];
  const float* Wq = (const float*)d_in[4];  const float* bq = (const float*)d_in[5];
  const float* Wk = (const float*)d_in[6];  const float* bk = (const float*)d_in[7];
  const float* Wv = (const float*)d_in[8];  const float* bv = (const float*)d_in[9];
  const float* Wo = (const float*)d_in[10]; const float* bo = (const float*)d_in[11];
  const float* W1 = (const float*)d_in[12]; const float* b1 = (const float*)d_in[13];
  const float* W2 = (const float*)d_in[14]; const float* b2 = (const float*)d_in[15];
  const float* g1 = (const float*)d_in[16]; const float* be1 = (const float*)d_in[17];
  const float* g2 = (const float*)d_in[18]; const float* be2 = (const float*)d_in[19];
  const float* lm_qw = (const float*)d_in[20]; const float* lm_qb = (const float*)d_in[21];
  const float* lm_kw = (const float*)d_in[22]; const float* lm_kb = (const float*)d_in[23];
  const float* gn = (const float*)d_in[24]; const float* bn = (const float*)d_in[25];
  const float* fc_w = (const float*)d_in[26]; const float* fc_b = (const float*)d_in[27];
  float* out = (float*)d_out;

  const size_t ROWS = (size_t)B_ * L_;     // 8000
  u16* qkv16 = (u16*)d_ws;                               // [8000][1792]
  u16* ctx16 = qkv16 + ROWS * QKVS;                      // [8000][512]
  u16* ffn1  = qkv16;                                    // [8000][2048] alias (qkv+ctx)
  u16* h16   = ctx16 + ROWS * DM_;                       // [8000][512]
  u16* t16   = h16 + ROWS * DM_;                         // [8000][512]
  u16* vtg   = t16 + ROWS * DM_;                         // [64][64][1024] dedicated
                                                         // (tail keys keep 0xAA poison =
                                                         //  finite bf16; P=0 -> safe)
  u16* Wqkv_t = vtg + (size_t)64 * 64 * 1024;            // [NL][1792][512]
  u16* Wo_t   = Wqkv_t + (size_t)NL_ * QKVS * DM_;       // [NL][512][512]
  u16* W1_t   = Wo_t + (size_t)NL_ * DM_ * DM_;          // [NL][2048][512]
  u16* W2_t   = W1_t + (size_t)NL_ * DFF_ * DM_;         // [NL][512][2048]
  float* bqkv = (float*)(W2_t + (size_t)NL_ * DM_ * DFF_);

  transpose_w<<<dim3(16, 16, NL_), 256, 0, stream>>>(Wq, Wqkv_t, DM_, DM_, (size_t)DM_ * DM_, (size_t)QKVS * DM_, 0, DM_);
  transpose_w<<<dim3(16, 16, NL_), 256, 0, stream>>>(Wk, Wqkv_t, DM_, DM_, (size_t)DM_ * DM_, (size_t)QKVS * DM_, 512, DM_);
  transpose_w<<<dim3(16, 16, NL_), 256, 0, stream>>>(Wv, Wqkv_t, DM_, DM_, (size_t)DM_ * DM_, (size_t)QKVS * DM_, 1024, DM_);
  transpose_w<<<dim3(16, 16, NL_), 256, 0, stream>>>(Wo, Wo_t, DM_, DM_, (size_t)DM_ * DM_, (size_t)DM_ * DM_, 0, DM_);
  transpose_w<<<dim3(64, 16, NL_), 256, 0, stream>>>(W1, W1_t, DM_, DFF_, (size_t)DM_ * DFF_, (size_t)DFF_ * DM_, 0, DM_);
  transpose_w<<<dim3(16, 64, NL_), 256, 0, stream>>>(W2, W2_t, DFF_, DM_, (size_t)DFF_ * DM_, (size_t)DM_ * DFF_, 0, DFF_);
  wfuse_kernel<<<dim3(H_, 2, NL_), 256, 0, stream>>>(Wq, Wk, lm_qw, lm_kw, Wqkv_t);
  concat_bias<<<NL_ * QKVS / 256, 256, 0, stream>>>(bq, bk, bv, lm_qw, lm_qb, lm_kw, lm_kb, bqkv);

  embed_kernel<<<dim3((unsigned)ROWS), 512, 0, stream>>>(x, emb_w, emb_b, pe, h16);

  dim3 g_qkv(QKVS / 128, 63);    // (14, 63)
  dim3 g_ffn1(DFF_ / 128, 63);
  dim3 g_n512(DM_ / 64, 63);
  dim3 g_attn(1024);

  for (int i = 0; i < NL_; i++) {
    gemm16<128><<<g_qkv, 256, 0, stream>>>(h16, Wqkv_t + (size_t)i * QKVS * DM_,
        bqkv + i * QKVS, nullptr, qkv16, vtg, 8000, DM_, QKVS, 0, 512, C_QS);

    attn_mfma_kernel<<<g_attn, 256, 0, stream>>>(qkv16, vtg, ctx16);

    gemm16<64><<<g_n512, 256, 0, stream>>>(ctx16, Wo_t + (size_t)i * DM_ * DM_,
        bo + i * DM_, h16, t16, nullptr, 8000, DM_, DM_, 0, 0, 1.0f);
    ln_kernel<<<dim3((unsigned)ROWS), 256, 0, stream>>>(t16, g1 + i * DM_, be1 + i * DM_, h16);

    gemm16<128><<<g_ffn1, 256, 0, stream>>>(h16, W1_t + (size_t)i * DFF_ * DM_,
        b1 + i * DFF_, nullptr, ffn1, nullptr, 8000, DM_, DFF_, 1, 0, 1.0f);
    gemm16<64><<<g_n512, 256, 0, stream>>>(ffn1, W2_t + (size_t)i * DM_ * DFF_,
        b2 + i * DM_, nullptr, t16, nullptr, 8000, DFF_, DM_, 0, 0, 1.0f);

    ln2x_kernel<<<dim3((unsigned)ROWS), 256, 0, stream>>>(h16, t16, g2 + i * DM_, be2 + i * DM_, h16);
  }

  final_kernel<<<B_, 512, 0, stream>>>(h16, gn, bn, fc_w, fc_b, out);
}